// Round 1
// 640.828 us; speedup vs baseline: 1.2105x; 1.2105x over previous
//
#include <hip/hip_runtime.h>
#include <hip/hip_bf16.h>
#include <stdint.h>

// Batched expert FFN: out = relu(x @ w1 + b1) @ w2 + b2
// E=8, T=2048, D=1024, H=4096, fp32 in/out, bf16 MFMA compute (fp32 accum).
//
// Round 4: replace m97-style 128^2/BK=32 GEMM (550 TF, barrier-drain bound)
// with the 256^2 8-phase template: BK=64, 512 thr (2x4 waves), 128 KiB LDS
// double-buffer, XOR-swizzled LDS (linear gload_lds dest + inverse-swizzled
// global source + swizzled ds_read), counted s_waitcnt vmcnt(4) once per
// K-tile (never 0 in steady state), raw s_barrier, setprio(1) around MFMA.

using frag8 = __attribute__((ext_vector_type(8))) short;   // 8 bf16 (4 VGPRs)
using f32x4 = __attribute__((ext_vector_type(4))) float;   // MFMA C/D

constexpr int E = 8, T = 2048, D = 1024, H = 4096;
constexpr int BM = 256, BN = 256, BK = 64;

__device__ __forceinline__ ushort f2bf(float f) {
    union { float f; uint32_t u; } v; v.f = f;
    return (ushort)((v.u + 0x7FFFu + ((v.u >> 16) & 1u)) >> 16);  // RTNE
}

__device__ __forceinline__ void load16_to_lds(const void* g, void* l) {
    __builtin_amdgcn_global_load_lds(
        (const __attribute__((address_space(1))) uint32_t*)g,
        (__attribute__((address_space(3))) uint32_t*)l, 16, 0, 0);
}

// ---------- prep kernels (unchanged from round 3) ----------

__global__ __launch_bounds__(256) void cvt_bf16_kernel(
    const float* __restrict__ in, ushort* __restrict__ out) {
    const size_t i = ((size_t)blockIdx.x * 256 + threadIdx.x) * 4;
    const float4 v = *(const float4*)(in + i);
    ushort4 o;
    o.x = f2bf(v.x); o.y = f2bf(v.y); o.z = f2bf(v.z); o.w = f2bf(v.w);
    *(ushort4*)(out + i) = o;
}

__global__ __launch_bounds__(256) void transpose_cvt_kernel(
    const float* __restrict__ in, ushort* __restrict__ out, int K, int N) {
    __shared__ __align__(16) ushort tile[64][72];
    const int e = blockIdx.z;
    const int k0 = blockIdx.y * 64, n0 = blockIdx.x * 64;
    const float* ie = in + (size_t)e * K * N + (size_t)k0 * N + n0;
    ushort* oe = out + (size_t)e * N * K + (size_t)n0 * K + k0;
    const int t = threadIdx.x;
    const int lk = t >> 2;
    const int ln = (t & 3) * 16;
#pragma unroll
    for (int v = 0; v < 4; ++v) {
        const float4 f = *(const float4*)(ie + (size_t)lk * N + ln + v * 4);
        tile[ln + v * 4 + 0][lk] = f2bf(f.x);
        tile[ln + v * 4 + 1][lk] = f2bf(f.y);
        tile[ln + v * 4 + 2][lk] = f2bf(f.z);
        tile[ln + v * 4 + 3][lk] = f2bf(f.w);
    }
    __syncthreads();
    const int on = t >> 2;
    const int ok = (t & 3) * 16;
#pragma unroll
    for (int v = 0; v < 2; ++v)
        *(frag8*)(oe + (size_t)on * K + ok + v * 8) = *(const frag8*)&tile[on][ok + v * 8];
}

// ---------- 256^2 8-phase GEMM ----------
// A: bf16 [E][T][K] row-major; B: bf16 [E][N][K]; bias fp32 [E][N].
// grid = E * (T/256) * (N/256); bid&7 = expert (XCD), M-fastest within.
template <bool RELU_BF16>
__global__ __launch_bounds__(512, 2) void gemm256_kernel(
    const ushort* __restrict__ A, const ushort* __restrict__ Bm,
    const float* __restrict__ bias, void* __restrict__ Cout,
    const int K, const int N) {
    // [buf p: A tile 32K | B tile 32K] x2 buffers = 128 KiB
    __shared__ __align__(16) char lds[131072];

    const int bid = blockIdx.x;
    const int e = bid & 7;
    const int s = bid >> 3;
    const int m0 = (s & 7) * BM;       // M-fastest: B n-slab stays L2-hot
    const int n0 = (s >> 3) * BN;

    const ushort* Ae = A + (size_t)e * T * K + (size_t)m0 * K;
    const ushort* Be = Bm + (size_t)e * N * K + (size_t)n0 * K;

    const int tid = threadIdx.x;
    const int lane = tid & 63;
    const int wave = tid >> 6;
    const int wm = wave >> 2;          // 0..1 : 128 M-rows each
    const int wn = wave & 3;           // 0..3 : 64 N-cols each
    const int col = lane & 15;
    const int quad = lane >> 4;

    // ---- staging geometry (inverse-swizzled global source, linear LDS dest) ----
    // chunk c = i*512 + wave*64 + lane; row = c>>3; source col-chunk = (c&7)^((c>>3)&7)
    const int scc = (lane & 7) ^ (lane >> 3);
    const int srow = wave * 8 + (lane >> 3);
    const ushort* gA0 = Ae + (size_t)srow * K + scc * 8;
    const ushort* gB0 = Be + (size_t)srow * K + scc * 8;
    const int ldsA0 = wave * 1024;            // + p*65536 + h*16384 + i*8192
    const int ldsB0 = 32768 + wave * 1024;

    // ---- frag-read swizzle: addr ^= ((row&7)<<4); row&7 == col&7 for all frags ----
    const int swz0 = ((quad ^ (col & 7)) << 4);
    const int swz1 = swz0 ^ 64;
    const int aRow = (wm * 128 + col) * 128;  // byte offset of lane's A frag row
    const int bRow = (wn * 64 + col) * 128;

    const int NT = K / BK;

#define STAGE_A(p, h, kk) do {                                          \
        const ushort* g_ = gA0 + (size_t)(h) * 128 * K + (kk);          \
        char* l_ = lds + (p) * 65536 + ldsA0 + (h) * 16384;             \
        load16_to_lds(g_, l_);                                          \
        load16_to_lds(g_ + (size_t)64 * K, l_ + 8192);                  \
    } while (0)
#define STAGE_B(p, h, kk) do {                                          \
        const ushort* g_ = gB0 + (size_t)(h) * 128 * K + (kk);          \
        char* l_ = lds + (p) * 65536 + ldsB0 + (h) * 16384;             \
        load16_to_lds(g_, l_);                                          \
        load16_to_lds(g_ + (size_t)64 * K, l_ + 8192);                  \
    } while (0)
#define MFMA(a, b, c) __builtin_amdgcn_mfma_f32_16x16x32_bf16((a), (b), (c), 0, 0, 0)

    f32x4 acc[8][4] = {};
    frag8 A0f[8], A1f[8], Bf[4];

    // ---- prologue: tile0 fully + tile1 A-halves; B(1) staged in iter 0 ----
    STAGE_A(0, 0, 0); STAGE_A(0, 1, 0);
    STAGE_B(0, 0, 0); STAGE_B(0, 1, 0);
    STAGE_A(1, 0, BK); STAGE_A(1, 1, BK);
    asm volatile("s_waitcnt vmcnt(4)" ::: "memory");   // tile0 (oldest 8) landed
    __builtin_amdgcn_s_barrier();
    __builtin_amdgcn_sched_barrier(0);

    for (int u = 0; u < NT; ++u) {
        const int p = u & 1, pn = p ^ 1;
        const int kB = (u + 1) * BK;   // B staged 1 tile ahead (other buffer)
        const int kA = (u + 2) * BK;   // A staged 2 tiles ahead (this buffer)
        const bool stB = (u + 1 < NT), stA = (u + 2 < NT);
        const char* aT = lds + p * 65536 + aRow;
        const char* bT = lds + p * 65536 + 32768 + bRow;

        // ======== phase 1: quadrant (mh0, nh0) — 12 ds_read ========
#pragma unroll
        for (int i = 0; i < 4; ++i) {
            A0f[i * 2 + 0] = *(const frag8*)(aT + i * 2048 + swz0);
            A0f[i * 2 + 1] = *(const frag8*)(aT + i * 2048 + swz1);
        }
#pragma unroll
        for (int j = 0; j < 2; ++j) {
            Bf[j * 2 + 0] = *(const frag8*)(bT + j * 2048 + swz0);
            Bf[j * 2 + 1] = *(const frag8*)(bT + j * 2048 + swz1);
        }
        if (stB) STAGE_B(pn, 0, kB);
        __builtin_amdgcn_s_barrier();
        asm volatile("s_waitcnt lgkmcnt(0)" ::: "memory");
        __builtin_amdgcn_sched_barrier(0);
        __builtin_amdgcn_s_setprio(1);
#pragma unroll
        for (int i = 0; i < 4; ++i)
#pragma unroll
            for (int j = 0; j < 2; ++j) {
                acc[i][j] = MFMA(A0f[i * 2 + 0], Bf[j * 2 + 0], acc[i][j]);
                acc[i][j] = MFMA(A0f[i * 2 + 1], Bf[j * 2 + 1], acc[i][j]);
            }
        __builtin_amdgcn_s_setprio(0);
        __builtin_amdgcn_s_barrier();
        __builtin_amdgcn_sched_barrier(0);

        // ======== phase 2: (mh1, nh0) — 8 ds_read, B reused ========
#pragma unroll
        for (int i = 0; i < 4; ++i) {
            A1f[i * 2 + 0] = *(const frag8*)(aT + 8192 + i * 2048 + swz0);
            A1f[i * 2 + 1] = *(const frag8*)(aT + 8192 + i * 2048 + swz1);
        }
        if (stB) STAGE_B(pn, 1, kB);
        __builtin_amdgcn_s_barrier();
        asm volatile("s_waitcnt lgkmcnt(0)" ::: "memory");
        __builtin_amdgcn_sched_barrier(0);
        __builtin_amdgcn_s_setprio(1);
#pragma unroll
        for (int i = 0; i < 4; ++i)
#pragma unroll
            for (int j = 0; j < 2; ++j) {
                acc[4 + i][j] = MFMA(A1f[i * 2 + 0], Bf[j * 2 + 0], acc[4 + i][j]);
                acc[4 + i][j] = MFMA(A1f[i * 2 + 1], Bf[j * 2 + 1], acc[4 + i][j]);
            }
        __builtin_amdgcn_s_setprio(0);
        __builtin_amdgcn_s_barrier();
        __builtin_amdgcn_sched_barrier(0);

        // ======== phase 3: (mh1, nh1) — 4 ds_read; A-halves now released ========
#pragma unroll
        for (int j = 0; j < 2; ++j) {
            Bf[j * 2 + 0] = *(const frag8*)(bT + 4096 + j * 2048 + swz0);
            Bf[j * 2 + 1] = *(const frag8*)(bT + 4096 + j * 2048 + swz1);
        }
        if (stA) STAGE_A(p, 0, kA);   // safe: A last read in ph2, barrier between
        __builtin_amdgcn_s_barrier();
        asm volatile("s_waitcnt lgkmcnt(0)" ::: "memory");
        __builtin_amdgcn_sched_barrier(0);
        __builtin_amdgcn_s_setprio(1);
#pragma unroll
        for (int i = 0; i < 4; ++i)
#pragma unroll
            for (int j = 0; j < 2; ++j) {
                acc[4 + i][2 + j] = MFMA(A1f[i * 2 + 0], Bf[j * 2 + 0], acc[4 + i][2 + j]);
                acc[4 + i][2 + j] = MFMA(A1f[i * 2 + 1], Bf[j * 2 + 1], acc[4 + i][2 + j]);
            }
        __builtin_amdgcn_s_setprio(0);
        __builtin_amdgcn_s_barrier();
        __builtin_amdgcn_sched_barrier(0);

        // ======== phase 4: (mh0, nh1) — 0 ds_read (A0f/Bf in regs) ========
        if (stA) STAGE_A(p, 1, kA);
        __builtin_amdgcn_s_barrier();
        __builtin_amdgcn_sched_barrier(0);
        __builtin_amdgcn_s_setprio(1);
#pragma unroll
        for (int i = 0; i < 4; ++i)
#pragma unroll
            for (int j = 0; j < 2; ++j) {
                acc[i][2 + j] = MFMA(A0f[i * 2 + 0], Bf[j * 2 + 0], acc[i][2 + j]);
                acc[i][2 + j] = MFMA(A0f[i * 2 + 1], Bf[j * 2 + 1], acc[i][2 + j]);
            }
        __builtin_amdgcn_s_setprio(0);
        // counted wait: 4 newest in flight = A(u+2); everything tile u+1 needs
        // is older. Drain fully only when no A-stage was issued this iter.
        if (stA) {
            asm volatile("s_waitcnt vmcnt(4)" ::: "memory");
        } else if (stB) {
            asm volatile("s_waitcnt vmcnt(0)" ::: "memory");
        }
        __builtin_amdgcn_s_barrier();
        __builtin_amdgcn_sched_barrier(0);
    }

    // ---- epilogue: C/D layout col=lane&15, row=quad*4+r (verified round 3) ----
    const float* be = bias + (size_t)e * N;
#pragma unroll
    for (int j = 0; j < 4; ++j) {
        const int nn = n0 + wn * 64 + j * 16 + col;
        const float bv = be[nn];
#pragma unroll
        for (int i = 0; i < 8; ++i) {
            const int mb = m0 + wm * 128 + i * 16 + quad * 4;
#pragma unroll
            for (int r = 0; r < 4; ++r) {
                float v = acc[i][j][r] + bv;
                if (RELU_BF16) {
                    v = v > 0.f ? v : 0.f;
                    ((ushort*)Cout)[(size_t)e * T * N + (size_t)(mb + r) * N + nn] = f2bf(v);
                } else {
                    ((float*)Cout)[(size_t)e * T * N + (size_t)(mb + r) * N + nn] = v;
                }
            }
        }
    }
#undef STAGE_A
#undef STAGE_B
#undef MFMA
}

// ---------- round-1 fallback (ws too small for prep regions) ----------

constexpr int FBM = 128, FBN = 128, FBK = 32;
constexpr int FLDK = FBK + 16;

__global__ __launch_bounds__(256) void fb_gemm1_kernel(
    const float* __restrict__ x, const float* __restrict__ w1,
    const float* __restrict__ b1, ushort* __restrict__ y1) {
    __shared__ __align__(16) ushort As[FBM * FLDK];
    __shared__ __align__(16) ushort Bs[FBN * FLDK];
    const int e = blockIdx.z, m0 = blockIdx.y * FBM, n0 = blockIdx.x * FBN;
    const float* xa = x + (size_t)e * T * D + (size_t)m0 * D;
    const float* wb = w1 + (size_t)e * D * H;
    const int tid = threadIdx.x, lane = tid & 63, wave = tid >> 6;
    const int waveM = (wave >> 1) * 64, waveN = (wave & 1) * 64;
    const int col = lane & 15, quad = lane >> 4;
    const int ar = tid >> 3, ak = (tid & 7) * 4;
    const int bn = tid & 127, bk = (tid >> 7) * 16;
    f32x4 acc[4][4] = {};
    for (int k0 = 0; k0 < D; k0 += FBK) {
#pragma unroll
        for (int p = 0; p < 4; ++p) {
            const float4 v = *(const float4*)(xa + (size_t)(ar + 32 * p) * D + k0 + ak);
            ushort* dst = &As[(ar + 32 * p) * FLDK + ak];
            dst[0] = f2bf(v.x); dst[1] = f2bf(v.y); dst[2] = f2bf(v.z); dst[3] = f2bf(v.w);
        }
        {
            ushort tmp[16];
#pragma unroll
            for (int j = 0; j < 16; ++j)
                tmp[j] = f2bf(wb[(size_t)(k0 + bk + j) * H + n0 + bn]);
            ushort* dst = &Bs[bn * FLDK + bk];
#pragma unroll
            for (int j = 0; j < 16; ++j) dst[j] = tmp[j];
        }
        __syncthreads();
        frag8 af[4], bf[4];
#pragma unroll
        for (int i = 0; i < 4; ++i) {
            af[i] = *(const frag8*)&As[(waveM + i * 16 + col) * FLDK + quad * 8];
            bf[i] = *(const frag8*)&Bs[(waveN + i * 16 + col) * FLDK + quad * 8];
        }
#pragma unroll
        for (int i = 0; i < 4; ++i)
#pragma unroll
            for (int j = 0; j < 4; ++j)
                acc[i][j] = __builtin_amdgcn_mfma_f32_16x16x32_bf16(af[i], bf[j], acc[i][j], 0, 0, 0);
        __syncthreads();
    }
    const float* be = b1 + (size_t)e * H;
    ushort* ye = y1 + (size_t)e * T * H;
#pragma unroll
    for (int j = 0; j < 4; ++j) {
        const int n = n0 + waveN + j * 16 + col;
        const float bias = be[n];
#pragma unroll
        for (int i = 0; i < 4; ++i) {
            const int mb = m0 + waveM + i * 16 + quad * 4;
#pragma unroll
            for (int r = 0; r < 4; ++r) {
                float v = acc[i][j][r] + bias;
                v = v > 0.f ? v : 0.f;
                ye[(size_t)(mb + r) * H + n] = f2bf(v);
            }
        }
    }
}

__global__ __launch_bounds__(256) void fb_gemm2_kernel(
    const ushort* __restrict__ y1, const float* __restrict__ w2,
    const float* __restrict__ b2, float* __restrict__ out) {
    __shared__ __align__(16) ushort As[FBM * FLDK];
    __shared__ __align__(16) ushort Bs[FBN * FLDK];
    const int e = blockIdx.z, m0 = blockIdx.y * FBM, n0 = blockIdx.x * FBN;
    const ushort* ya = y1 + (size_t)e * T * H + (size_t)m0 * H;
    const float* wb = w2 + (size_t)e * H * D;
    const int tid = threadIdx.x, lane = tid & 63, wave = tid >> 6;
    const int waveM = (wave >> 1) * 64, waveN = (wave & 1) * 64;
    const int col = lane & 15, quad = lane >> 4;
    const int ar = tid >> 2, ak = (tid & 3) * 8;
    const int bn = tid & 127, bk = (tid >> 7) * 16;
    f32x4 acc[4][4] = {};
    for (int k0 = 0; k0 < H; k0 += FBK) {
#pragma unroll
        for (int p = 0; p < 2; ++p)
            *(frag8*)&As[(ar + 64 * p) * FLDK + ak] =
                *(const frag8*)(ya + (size_t)(ar + 64 * p) * H + k0 + ak);
        {
            ushort tmp[16];
#pragma unroll
            for (int j = 0; j < 16; ++j)
                tmp[j] = f2bf(wb[(size_t)(k0 + bk + j) * D + n0 + bn]);
            ushort* dst = &Bs[bn * FLDK + bk];
#pragma unroll
            for (int j = 0; j < 16; ++j) dst[j] = tmp[j];
        }
        __syncthreads();
        frag8 af[4], bf[4];
#pragma unroll
        for (int i = 0; i < 4; ++i) {
            af[i] = *(const frag8*)&As[(waveM + i * 16 + col) * FLDK + quad * 8];
            bf[i] = *(const frag8*)&Bs[(waveN + i * 16 + col) * FLDK + quad * 8];
        }
#pragma unroll
        for (int i = 0; i < 4; ++i)
#pragma unroll
            for (int j = 0; j < 4; ++j)
                acc[i][j] = __builtin_amdgcn_mfma_f32_16x16x32_bf16(af[i], bf[j], acc[i][j], 0, 0, 0);
        __syncthreads();
    }
    const float* be = b2 + (size_t)e * D;
    float* oe = out + (size_t)e * T * D;
#pragma unroll
    for (int j = 0; j < 4; ++j) {
        const int n = n0 + waveN + j * 16 + col;
        const float bias = be[n];
#pragma unroll
        for (int i = 0; i < 4; ++i) {
            const int mb = m0 + waveM + i * 16 + quad * 4;
#pragma unroll
            for (int r = 0; r < 4; ++r)
                oe[(size_t)(mb + r) * D + n] = acc[i][j][r] + bias;
        }
    }
}

extern "C" void kernel_launch(void* const* d_in, const int* in_sizes, int n_in,
                              void* d_out, int out_size, void* d_ws, size_t ws_size,
                              hipStream_t stream) {
    const float* x  = (const float*)d_in[0];   // [E,T,D]
    const float* w1 = (const float*)d_in[1];   // [E,D,H]
    const float* b1 = (const float*)d_in[2];   // [E,1,H]
    const float* w2 = (const float*)d_in[3];   // [E,H,D]
    const float* b2 = (const float*)d_in[4];   // [E,1,D]
    float* out = (float*)d_out;                // [E,T,D]

    const size_t y1_bytes = (size_t)E * T * H * 2;  // 128 MB
    const size_t wt_bytes = (size_t)E * D * H * 2;  //  64 MB (shared w1t/w2t)
    const size_t xb_bytes = (size_t)E * T * D * 2;  //  32 MB
    const size_t need = y1_bytes + wt_bytes + xb_bytes;  // 224 MB

    if (ws_size >= need) {
        ushort* y1 = (ushort*)d_ws;
        ushort* wt = (ushort*)((char*)d_ws + y1_bytes);
        ushort* xb = (ushort*)((char*)d_ws + y1_bytes + wt_bytes);

        // 1. x -> bf16
        cvt_bf16_kernel<<<(E * T * D) / (256 * 4), 256, 0, stream>>>(x, xb);
        // 2. w1 [E][D][H] -> wt [E][H][D] bf16
        transpose_cvt_kernel<<<dim3(H / 64, D / 64, E), 256, 0, stream>>>(w1, wt, D, H);
        // 3. gemm1: y1 = relu(xb @ w1 + b1), bf16   (8x8x16 = 1024 blocks)
        gemm256_kernel<true><<<E * (T / BM) * (H / BN), 512, 0, stream>>>(xb, wt, b1, y1, D, H);
        // 4. w2 [E][H][D] -> wt [E][D][H] bf16 (region reuse)
        transpose_cvt_kernel<<<dim3(D / 64, H / 64, E), 256, 0, stream>>>(w2, wt, H, D);
        // 5. gemm2: out = y1 @ w2 + b2, fp32        (8x8x4 = 256 blocks)
        gemm256_kernel<false><<<E * (T / BM) * (D / BN), 512, 0, stream>>>(y1, wt, b2, out, H, D);
    } else {
        ushort* y1 = (ushort*)d_ws;
        fb_gemm1_kernel<<<dim3(H / FBN, T / FBM, E), 256, 0, stream>>>(x, w1, b1, y1);
        fb_gemm2_kernel<<<dim3(D / FBN, T / FBM, E), 256, 0, stream>>>(y1, w2, b2, out);
    }
}

// Round 2
// 602.043 us; speedup vs baseline: 1.2885x; 1.0644x over previous
//
#include <hip/hip_runtime.h>
#include <hip/hip_bf16.h>
#include <stdint.h>

// Batched expert FFN: out = relu(x @ w1 + b1) @ w2 + b2
// E=8, T=2048, D=1024, H=4096, fp32 in/out, bf16 MFMA compute (fp32 accum).
//
// Round 5: deepen the stage pipeline to the m201 reference schedule.
// Interleaved wave->output ownership (rows wm*64+{0..63} u {128+wm*64+..},
// cols wn*32+{0..31} u {128+wn*32+..}) so ph1 completes ALL reads of A-h0
// and B-h0, ph2 A-h1, ph3 B-h1. That legalizes staging each half 4-7 phases
// before first use: ph1 B-h1(u+1)->pn, ph2 A-h0(u+2)->p, ph3 A-h1(u+2)->p,
// ph4 B-h0(u+2)->p, single s_waitcnt vmcnt(6) per K-tile (3 halves in
// flight). Round 4 staged B(u+1) only 2-3 phases before the wait -> vmcnt
// stall every K-tile boundary (MfmaUtil 29.5%).

using frag8 = __attribute__((ext_vector_type(8))) short;   // 8 bf16 (4 VGPRs)
using f32x4 = __attribute__((ext_vector_type(4))) float;   // MFMA C/D

constexpr int E = 8, T = 2048, D = 1024, H = 4096;
constexpr int BM = 256, BN = 256, BK = 64;

__device__ __forceinline__ ushort f2bf(float f) {
    union { float f; uint32_t u; } v; v.f = f;
    return (ushort)((v.u + 0x7FFFu + ((v.u >> 16) & 1u)) >> 16);  // RTNE
}

__device__ __forceinline__ void load16_to_lds(const void* g, void* l) {
    __builtin_amdgcn_global_load_lds(
        (const __attribute__((address_space(1))) uint32_t*)g,
        (__attribute__((address_space(3))) uint32_t*)l, 16, 0, 0);
}

// ---------- prep kernels (unchanged) ----------

__global__ __launch_bounds__(256) void cvt_bf16_kernel(
    const float* __restrict__ in, ushort* __restrict__ out) {
    const size_t i = ((size_t)blockIdx.x * 256 + threadIdx.x) * 4;
    const float4 v = *(const float4*)(in + i);
    ushort4 o;
    o.x = f2bf(v.x); o.y = f2bf(v.y); o.z = f2bf(v.z); o.w = f2bf(v.w);
    *(ushort4*)(out + i) = o;
}

__global__ __launch_bounds__(256) void transpose_cvt_kernel(
    const float* __restrict__ in, ushort* __restrict__ out, int K, int N) {
    __shared__ __align__(16) ushort tile[64][72];
    const int e = blockIdx.z;
    const int k0 = blockIdx.y * 64, n0 = blockIdx.x * 64;
    const float* ie = in + (size_t)e * K * N + (size_t)k0 * N + n0;
    ushort* oe = out + (size_t)e * N * K + (size_t)n0 * K + k0;
    const int t = threadIdx.x;
    const int lk = t >> 2;
    const int ln = (t & 3) * 16;
#pragma unroll
    for (int v = 0; v < 4; ++v) {
        const float4 f = *(const float4*)(ie + (size_t)lk * N + ln + v * 4);
        tile[ln + v * 4 + 0][lk] = f2bf(f.x);
        tile[ln + v * 4 + 1][lk] = f2bf(f.y);
        tile[ln + v * 4 + 2][lk] = f2bf(f.z);
        tile[ln + v * 4 + 3][lk] = f2bf(f.w);
    }
    __syncthreads();
    const int on = t >> 2;
    const int ok = (t & 3) * 16;
#pragma unroll
    for (int v = 0; v < 2; ++v)
        *(frag8*)(oe + (size_t)on * K + ok + v * 8) = *(const frag8*)&tile[on][ok + v * 8];
}

// ---------- 256^2 8-phase GEMM, m201 stage schedule ----------
// A: bf16 [E][T][K] row-major; B: bf16 [E][N][K]; bias fp32 [E][N].
template <bool RELU_BF16>
__global__ __launch_bounds__(512, 2) void gemm256_kernel(
    const ushort* __restrict__ A, const ushort* __restrict__ Bm,
    const float* __restrict__ bias, void* __restrict__ Cout,
    const int K, const int N) {
    // [buf p: A tile 32K | B tile 32K] x2 buffers = 128 KiB
    __shared__ __align__(16) char lds[131072];

    const int bid = blockIdx.x;
    const int e = bid & 7;             // expert == XCD
    const int s = bid >> 3;
    const int m0 = (s & 7) * BM;       // M-fastest: B n-slab stays L2-hot
    const int n0 = (s >> 3) * BN;

    const ushort* Ae = A + (size_t)e * T * K + (size_t)m0 * K;
    const ushort* Be = Bm + (size_t)e * N * K + (size_t)n0 * K;

    const int tid = threadIdx.x;
    const int lane = tid & 63;
    const int wave = tid >> 6;
    const int wm = wave >> 2;          // 0..1
    const int wn = wave & 3;           // 0..3
    const int col = lane & 15;
    const int quad = lane >> 4;

    // staging: inverse-swizzled global source, linear LDS dest (rule #21)
    const int scc = (lane & 7) ^ (lane >> 3);
    const int srow = wave * 8 + (lane >> 3);
    const ushort* gA0 = Ae + (size_t)srow * K + scc * 8;
    const ushort* gB0 = Be + (size_t)srow * K + scc * 8;
    const int ldsA0 = wave * 1024;            // + p*65536 + h*16384 + i*8192
    const int ldsB0 = 32768 + wave * 1024;

    // frag-read swizzle: addr ^= ((row&7)<<4); row&7 == col&7 for every frag
    // (all row bases are multiples of 8: wm*64, wn*32, i*16, 128).
    const int swz0 = ((quad ^ (col & 7)) << 4);
    const int swz1 = swz0 ^ 64;
    // interleaved ownership: rows wm*64+{0..63} and 128+wm*64+{0..63};
    //                        cols wn*32+{0..31} and 128+wn*32+{0..31}.
    const int aRow = (wm * 64 + col) * 128;   // byte base of A row-chunk0
    const int bRow = (wn * 32 + col) * 128;   // byte base of B col-chunk0

    const int NT = K / BK;

#define STAGE_A(p, h, kk) do {                                          \
        const ushort* g_ = gA0 + (size_t)(h) * 128 * K + (kk);          \
        char* l_ = lds + (p) * 65536 + ldsA0 + (h) * 16384;             \
        load16_to_lds(g_, l_);                                          \
        load16_to_lds(g_ + (size_t)64 * K, l_ + 8192);                  \
    } while (0)
#define STAGE_B(p, h, kk) do {                                          \
        const ushort* g_ = gB0 + (size_t)(h) * 128 * K + (kk);          \
        char* l_ = lds + (p) * 65536 + ldsB0 + (h) * 16384;             \
        load16_to_lds(g_, l_);                                          \
        load16_to_lds(g_ + (size_t)64 * K, l_ + 8192);                  \
    } while (0)
#define MFMA(a, b, c) __builtin_amdgcn_mfma_f32_16x16x32_bf16((a), (b), (c), 0, 0, 0)

    f32x4 acc[8][4] = {};
    frag8 A0f[8], A1f[8], Bf[4];   // Bf reused for col-chunk1 in ph3/ph4

    // ---- prologue: tile0 full + A-h0/A-h1/B-h0 of tile1 (14 loads) ----
    STAGE_A(0, 0, 0); STAGE_A(0, 1, 0);
    STAGE_B(0, 0, 0); STAGE_B(0, 1, 0);
    STAGE_A(1, 0, BK); STAGE_A(1, 1, BK); STAGE_B(1, 0, BK);
    asm volatile("s_waitcnt vmcnt(6)" ::: "memory");   // tile0 (oldest 8) landed
    __builtin_amdgcn_s_barrier();
    __builtin_amdgcn_sched_barrier(0);

#define TILE_ITER(u, p, pn) do {                                              \
        const int kB_ = ((u) + 1) * BK, kA_ = ((u) + 2) * BK;                 \
        const bool stB_ = (u) + 1 < NT, stA_ = (u) + 2 < NT;                  \
        const char* aT = lds + (p) * 65536 + aRow;                            \
        const char* bT = lds + (p) * 65536 + 32768 + bRow;                    \
        /* == ph1: (row-chunk0, col-chunk0) — 12 ds_read == */                \
        _Pragma("unroll")                                                     \
        for (int i = 0; i < 4; ++i) {                                         \
            A0f[i * 2 + 0] = *(const frag8*)(aT + i * 2048 + swz0);           \
            A0f[i * 2 + 1] = *(const frag8*)(aT + i * 2048 + swz1);           \
        }                                                                     \
        _Pragma("unroll")                                                     \
        for (int j = 0; j < 2; ++j) {                                         \
            Bf[j * 2 + 0] = *(const frag8*)(bT + j * 2048 + swz0);            \
            Bf[j * 2 + 1] = *(const frag8*)(bT + j * 2048 + swz1);            \
        }                                                                     \
        if (stB_) STAGE_B(pn, 1, kB_);                                        \
        __builtin_amdgcn_s_barrier();                                         \
        asm volatile("s_waitcnt lgkmcnt(0)" ::: "memory");                    \
        __builtin_amdgcn_sched_barrier(0);                                    \
        __builtin_amdgcn_s_setprio(1);                                        \
        _Pragma("unroll")                                                     \
        for (int i = 0; i < 4; ++i)                                           \
            _Pragma("unroll")                                                 \
            for (int j = 0; j < 2; ++j) {                                     \
                acc[i][j] = MFMA(A0f[i * 2 + 0], Bf[j * 2 + 0], acc[i][j]);   \
                acc[i][j] = MFMA(A0f[i * 2 + 1], Bf[j * 2 + 1], acc[i][j]);   \
            }                                                                 \
        __builtin_amdgcn_s_setprio(0);                                        \
        __builtin_amdgcn_s_barrier();                                         \
        __builtin_amdgcn_sched_barrier(0);                                    \
        /* == ph2: (row-chunk1, col-chunk0) — 8 ds_read; A-h0 reads done == */\
        _Pragma("unroll")                                                     \
        for (int i = 0; i < 4; ++i) {                                         \
            A1f[i * 2 + 0] = *(const frag8*)(aT + 16384 + i * 2048 + swz0);   \
            A1f[i * 2 + 1] = *(const frag8*)(aT + 16384 + i * 2048 + swz1);   \
        }                                                                     \
        if (stA_) STAGE_A(p, 0, kA_);                                         \
        __builtin_amdgcn_s_barrier();                                         \
        asm volatile("s_waitcnt lgkmcnt(0)" ::: "memory");                    \
        __builtin_amdgcn_sched_barrier(0);                                    \
        __builtin_amdgcn_s_setprio(1);                                        \
        _Pragma("unroll")                                                     \
        for (int i = 0; i < 4; ++i)                                           \
            _Pragma("unroll")                                                 \
            for (int j = 0; j < 2; ++j) {                                     \
                acc[4 + i][j] = MFMA(A1f[i * 2 + 0], Bf[j * 2 + 0], acc[4 + i][j]); \
                acc[4 + i][j] = MFMA(A1f[i * 2 + 1], Bf[j * 2 + 1], acc[4 + i][j]); \
            }                                                                 \
        __builtin_amdgcn_s_setprio(0);                                        \
        __builtin_amdgcn_s_barrier();                                         \
        __builtin_amdgcn_sched_barrier(0);                                    \
        /* == ph3: (row-chunk1, col-chunk1) — 4 ds_read; A-h1 reads done == */\
        _Pragma("unroll")                                                     \
        for (int j = 0; j < 2; ++j) {                                         \
            Bf[j * 2 + 0] = *(const frag8*)(bT + 16384 + j * 2048 + swz0);    \
            Bf[j * 2 + 1] = *(const frag8*)(bT + 16384 + j * 2048 + swz1);    \
        }                                                                     \
        if (stA_) STAGE_A(p, 1, kA_);                                         \
        __builtin_amdgcn_s_barrier();                                         \
        asm volatile("s_waitcnt lgkmcnt(0)" ::: "memory");                    \
        __builtin_amdgcn_sched_barrier(0);                                    \
        __builtin_amdgcn_s_setprio(1);                                        \
        _Pragma("unroll")                                                     \
        for (int i = 0; i < 4; ++i)                                           \
            _Pragma("unroll")                                                 \
            for (int j = 0; j < 2; ++j) {                                     \
                acc[4 + i][2 + j] = MFMA(A1f[i * 2 + 0], Bf[j * 2 + 0], acc[4 + i][2 + j]); \
                acc[4 + i][2 + j] = MFMA(A1f[i * 2 + 1], Bf[j * 2 + 1], acc[4 + i][2 + j]); \
            }                                                                 \
        __builtin_amdgcn_s_setprio(0);                                        \
        __builtin_amdgcn_s_barrier();                                         \
        __builtin_amdgcn_sched_barrier(0);                                    \
        /* == ph4: (row-chunk0, col-chunk1) — 0 ds_read; B-h0 reads done == */\
        if (stA_) STAGE_B(p, 0, kA_);                                         \
        __builtin_amdgcn_s_setprio(1);                                        \
        _Pragma("unroll")                                                     \
        for (int i = 0; i < 4; ++i)                                           \
            _Pragma("unroll")                                                 \
            for (int j = 0; j < 2; ++j) {                                     \
                acc[i][2 + j] = MFMA(A0f[i * 2 + 0], Bf[j * 2 + 0], acc[i][2 + j]); \
                acc[i][2 + j] = MFMA(A0f[i * 2 + 1], Bf[j * 2 + 1], acc[i][2 + j]); \
            }                                                                 \
        __builtin_amdgcn_s_setprio(0);                                        \
        /* in flight after wait: A-h0/A-h1/B-h0 of tile u+2 = 3 halves */     \
        if (stA_) {                                                           \
            asm volatile("s_waitcnt vmcnt(6)" ::: "memory");                  \
        } else if (stB_) {                                                    \
            asm volatile("s_waitcnt vmcnt(0)" ::: "memory");                  \
        }                                                                     \
        __builtin_amdgcn_s_barrier();                                         \
        __builtin_amdgcn_sched_barrier(0);                                    \
    } while (0)

    for (int v = 0; v < NT / 2; ++v) {
        TILE_ITER(2 * v, 0, 1);
        TILE_ITER(2 * v + 1, 1, 0);
    }
#undef TILE_ITER

    // ---- epilogue: interleaved ownership mapping ----
    const float* be = bias + (size_t)e * N;
#pragma unroll
    for (int j = 0; j < 4; ++j) {
        const int nn = n0 + wn * 32 + (j & 1) * 16 + (j >> 1) * 128 + col;
        const float bv = be[nn];
#pragma unroll
        for (int i = 0; i < 8; ++i) {
            const int mb = m0 + wm * 64 + (i & 3) * 16 + (i >> 2) * 128 + quad * 4;
#pragma unroll
            for (int r = 0; r < 4; ++r) {
                float v = acc[i][j][r] + bv;
                if (RELU_BF16) {
                    v = v > 0.f ? v : 0.f;
                    ((ushort*)Cout)[(size_t)e * T * N + (size_t)(mb + r) * N + nn] = f2bf(v);
                } else {
                    ((float*)Cout)[(size_t)e * T * N + (size_t)(mb + r) * N + nn] = v;
                }
            }
        }
    }
#undef STAGE_A
#undef STAGE_B
#undef MFMA
}

// ---------- round-1 fallback (ws too small for prep regions) ----------

constexpr int FBM = 128, FBN = 128, FBK = 32;
constexpr int FLDK = FBK + 16;

__global__ __launch_bounds__(256) void fb_gemm1_kernel(
    const float* __restrict__ x, const float* __restrict__ w1,
    const float* __restrict__ b1, ushort* __restrict__ y1) {
    __shared__ __align__(16) ushort As[FBM * FLDK];
    __shared__ __align__(16) ushort Bs[FBN * FLDK];
    const int e = blockIdx.z, m0 = blockIdx.y * FBM, n0 = blockIdx.x * FBN;
    const float* xa = x + (size_t)e * T * D + (size_t)m0 * D;
    const float* wb = w1 + (size_t)e * D * H;
    const int tid = threadIdx.x, lane = tid & 63, wave = tid >> 6;
    const int waveM = (wave >> 1) * 64, waveN = (wave & 1) * 64;
    const int col = lane & 15, quad = lane >> 4;
    const int ar = tid >> 3, ak = (tid & 7) * 4;
    const int bn = tid & 127, bk = (tid >> 7) * 16;
    f32x4 acc[4][4] = {};
    for (int k0 = 0; k0 < D; k0 += FBK) {
#pragma unroll
        for (int p = 0; p < 4; ++p) {
            const float4 v = *(const float4*)(xa + (size_t)(ar + 32 * p) * D + k0 + ak);
            ushort* dst = &As[(ar + 32 * p) * FLDK + ak];
            dst[0] = f2bf(v.x); dst[1] = f2bf(v.y); dst[2] = f2bf(v.z); dst[3] = f2bf(v.w);
        }
        {
            ushort tmp[16];
#pragma unroll
            for (int j = 0; j < 16; ++j)
                tmp[j] = f2bf(wb[(size_t)(k0 + bk + j) * H + n0 + bn]);
            ushort* dst = &Bs[bn * FLDK + bk];
#pragma unroll
            for (int j = 0; j < 16; ++j) dst[j] = tmp[j];
        }
        __syncthreads();
        frag8 af[4], bf[4];
#pragma unroll
        for (int i = 0; i < 4; ++i) {
            af[i] = *(const frag8*)&As[(waveM + i * 16 + col) * FLDK + quad * 8];
            bf[i] = *(const frag8*)&Bs[(waveN + i * 16 + col) * FLDK + quad * 8];
        }
#pragma unroll
        for (int i = 0; i < 4; ++i)
#pragma unroll
            for (int j = 0; j < 4; ++j)
                acc[i][j] = __builtin_amdgcn_mfma_f32_16x16x32_bf16(af[i], bf[j], acc[i][j], 0, 0, 0);
        __syncthreads();
    }
    const float* be = b1 + (size_t)e * H;
    ushort* ye = y1 + (size_t)e * T * H;
#pragma unroll
    for (int j = 0; j < 4; ++j) {
        const int n = n0 + waveN + j * 16 + col;
        const float bias = be[n];
#pragma unroll
        for (int i = 0; i < 4; ++i) {
            const int mb = m0 + waveM + i * 16 + quad * 4;
#pragma unroll
            for (int r = 0; r < 4; ++r) {
                float v = acc[i][j][r] + bias;
                v = v > 0.f ? v : 0.f;
                ye[(size_t)(mb + r) * H + n] = f2bf(v);
            }
        }
    }
}

__global__ __launch_bounds__(256) void fb_gemm2_kernel(
    const ushort* __restrict__ y1, const float* __restrict__ w2,
    const float* __restrict__ b2, float* __restrict__ out) {
    __shared__ __align__(16) ushort As[FBM * FLDK];
    __shared__ __align__(16) ushort Bs[FBN * FLDK];
    const int e = blockIdx.z, m0 = blockIdx.y * FBM, n0 = blockIdx.x * FBN;
    const ushort* ya = y1 + (size_t)e * T * H + (size_t)m0 * H;
    const float* wb = w2 + (size_t)e * H * D;
    const int tid = threadIdx.x, lane = tid & 63, wave = tid >> 6;
    const int waveM = (wave >> 1) * 64, waveN = (wave & 1) * 64;
    const int col = lane & 15, quad = lane >> 4;
    const int ar = tid >> 2, ak = (tid & 3) * 8;
    const int bn = tid & 127, bk = (tid >> 7) * 16;
    f32x4 acc[4][4] = {};
    for (int k0 = 0; k0 < H; k0 += FBK) {
#pragma unroll
        for (int p = 0; p < 2; ++p)
            *(frag8*)&As[(ar + 64 * p) * FLDK + ak] =
                *(const frag8*)(ya + (size_t)(ar + 64 * p) * H + k0 + ak);
        {
            ushort tmp[16];
#pragma unroll
            for (int j = 0; j < 16; ++j)
                tmp[j] = f2bf(wb[(size_t)(k0 + bk + j) * D + n0 + bn]);
            ushort* dst = &Bs[bn * FLDK + bk];
#pragma unroll
            for (int j = 0; j < 16; ++j) dst[j] = tmp[j];
        }
        __syncthreads();
        frag8 af[4], bf[4];
#pragma unroll
        for (int i = 0; i < 4; ++i) {
            af[i] = *(const frag8*)&As[(waveM + i * 16 + col) * FLDK + quad * 8];
            bf[i] = *(const frag8*)&Bs[(waveN + i * 16 + col) * FLDK + quad * 8];
        }
#pragma unroll
        for (int i = 0; i < 4; ++i)
#pragma unroll
            for (int j = 0; j < 4; ++j)
                acc[i][j] = __builtin_amdgcn_mfma_f32_16x16x32_bf16(af[i], bf[j], acc[i][j], 0, 0, 0);
        __syncthreads();
    }
    const float* be = b2 + (size_t)e * D;
    float* oe = out + (size_t)e * T * D;
#pragma unroll
    for (int j = 0; j < 4; ++j) {
        const int n = n0 + waveN + j * 16 + col;
        const float bias = be[n];
#pragma unroll
        for (int i = 0; i < 4; ++i) {
            const int mb = m0 + waveM + i * 16 + quad * 4;
#pragma unroll
            for (int r = 0; r < 4; ++r)
                oe[(size_t)(mb + r) * D + n] = acc[i][j][r] + bias;
        }
    }
}

extern "C" void kernel_launch(void* const* d_in, const int* in_sizes, int n_in,
                              void* d_out, int out_size, void* d_ws, size_t ws_size,
                              hipStream_t stream) {
    const float* x  = (const float*)d_in[0];   // [E,T,D]
    const float* w1 = (const float*)d_in[1];   // [E,D,H]
    const float* b1 = (const float*)d_in[2];   // [E,1,H]
    const float* w2 = (const float*)d_in[3];   // [E,H,D]
    const float* b2 = (const float*)d_in[4];   // [E,1,D]
    float* out = (float*)d_out;                // [E,T,D]

    const size_t y1_bytes = (size_t)E * T * H * 2;  // 128 MB
    const size_t wt_bytes = (size_t)E * D * H * 2;  //  64 MB (shared w1t/w2t)
    const size_t xb_bytes = (size_t)E * T * D * 2;  //  32 MB
    const size_t need = y1_bytes + wt_bytes + xb_bytes;  // 224 MB

    if (ws_size >= need) {
        ushort* y1 = (ushort*)d_ws;
        ushort* wt = (ushort*)((char*)d_ws + y1_bytes);
        ushort* xb = (ushort*)((char*)d_ws + y1_bytes + wt_bytes);

        // 1. x -> bf16
        cvt_bf16_kernel<<<(E * T * D) / (256 * 4), 256, 0, stream>>>(x, xb);
        // 2. w1 [E][D][H] -> wt [E][H][D] bf16
        transpose_cvt_kernel<<<dim3(H / 64, D / 64, E), 256, 0, stream>>>(w1, wt, D, H);
        // 3. gemm1: y1 = relu(xb @ w1 + b1), bf16   (8x8x16 = 1024 blocks)
        gemm256_kernel<true><<<E * (T / BM) * (H / BN), 512, 0, stream>>>(xb, wt, b1, y1, D, H);
        // 4. w2 [E][H][D] -> wt [E][D][H] bf16 (region reuse)
        transpose_cvt_kernel<<<dim3(D / 64, H / 64, E), 256, 0, stream>>>(w2, wt, H, D);
        // 5. gemm2: out = y1 @ w2 + b2, fp32        (8x8x4 = 256 blocks)
        gemm256_kernel<false><<<E * (T / BM) * (D / BN), 512, 0, stream>>>(y1, wt, b2, out, H, D);
    } else {
        ushort* y1 = (ushort*)d_ws;
        fb_gemm1_kernel<<<dim3(H / FBN, T / FBM, E), 256, 0, stream>>>(x, w1, b1, y1);
        fb_gemm2_kernel<<<dim3(D / FBN, T / FBM, E), 256, 0, stream>>>(y1, w2, b2, out);
    }
}

// Round 3
// 600.278 us; speedup vs baseline: 1.2923x; 1.0029x over previous
//
#include <hip/hip_runtime.h>
#include <hip/hip_bf16.h>
#include <stdint.h>

// Batched expert FFN: out = relu(x @ w1 + b1) @ w2 + b2
// E=8, T=2048, D=1024, H=4096, fp32 in/out, bf16 MFMA compute (fp32 accum).
//
// Round 6: (a) GEMM: remove manual lgkmcnt(0) full drains — let the compiler
// emit counted lgkmcnt interleaved into the MFMA cluster so the LDS read
// drain overlaps MFMA (round 2 serialized them: 5730 cy/K-tile vs m201's
// 3300). Keep barriers/setprio/vmcnt(6); one sched_barrier(0) per phase
// after the post-MFMA barrier (pins STAGE below the barrier — the only
// unsafe code motion). (b) transpose_cvt: coalesced 256B-row reads +
// ushort2 LDS writes (<=2-way banks) replacing 8-way-conflict scalar
// column writes.

using frag8 = __attribute__((ext_vector_type(8))) short;   // 8 bf16 (4 VGPRs)
using f32x4 = __attribute__((ext_vector_type(4))) float;   // MFMA C/D

constexpr int E = 8, T = 2048, D = 1024, H = 4096;
constexpr int BM = 256, BN = 256, BK = 64;

__device__ __forceinline__ ushort f2bf(float f) {
    union { float f; uint32_t u; } v; v.f = f;
    return (ushort)((v.u + 0x7FFFu + ((v.u >> 16) & 1u)) >> 16);  // RTNE
}

__device__ __forceinline__ void load16_to_lds(const void* g, void* l) {
    __builtin_amdgcn_global_load_lds(
        (const __attribute__((address_space(1))) uint32_t*)g,
        (__attribute__((address_space(3))) uint32_t*)l, 16, 0, 0);
}

// ---------- prep kernels ----------

__global__ __launch_bounds__(256) void cvt_bf16_kernel(
    const float* __restrict__ in, ushort* __restrict__ out) {
    const size_t i = ((size_t)blockIdx.x * 256 + threadIdx.x) * 4;
    const float4 v = *(const float4*)(in + i);
    ushort4 o;
    o.x = f2bf(v.x); o.y = f2bf(v.y); o.z = f2bf(v.z); o.w = f2bf(v.w);
    *(ushort4*)(out + i) = o;
}

// in[e][K][N] fp32 -> out[e][N][K] bf16; 64x64 tiles.
// Reads: thread t covers rows 2*(t>>4)+{0,1} (+32/pass), cols (t&15)*4..+4
//   -> each 16-lane group reads 256B contiguous (fully coalesced).
// LDS: tile[n][k] ushort, row pad 72 (36 words): bank step per n = 36%32=4,
//   16 lanes x step4 = 2-way max (free). ushort2 writes (k even pairs).
// Stores: thread t writes out row t>>2, k-chunk (t&3)*16 as 2x frag8
//   -> 4-lane groups write 128B contiguous (coalesced).
__global__ __launch_bounds__(256) void transpose_cvt_kernel(
    const float* __restrict__ in, ushort* __restrict__ out, int K, int N) {
    __shared__ __align__(16) ushort tile[64][72];
    const int e = blockIdx.z;
    const int k0 = blockIdx.y * 64, n0 = blockIdx.x * 64;
    const float* ie = in + (size_t)e * K * N + (size_t)k0 * N + n0;
    ushort* oe = out + (size_t)e * N * K + (size_t)n0 * K + k0;
    const int t = threadIdx.x;
    const int lc = (t & 15) * 4;       // col (n) base
    const int lr = (t >> 4) * 2;       // row (k) base, even
#pragma unroll
    for (int pass = 0; pass < 2; ++pass) {
        const int r = lr + pass * 32;
        const float4 f0 = *(const float4*)(ie + (size_t)r * N + lc);
        const float4 f1 = *(const float4*)(ie + (size_t)(r + 1) * N + lc);
        const float x0[4] = {f0.x, f0.y, f0.z, f0.w};
        const float x1[4] = {f1.x, f1.y, f1.z, f1.w};
#pragma unroll
        for (int i = 0; i < 4; ++i) {
            ushort2 p; p.x = f2bf(x0[i]); p.y = f2bf(x1[i]);
            *(ushort2*)&tile[lc + i][r] = p;   // 4B-aligned (r even)
        }
    }
    __syncthreads();
    const int on = t >> 2;
    const int ok = (t & 3) * 16;
#pragma unroll
    for (int v = 0; v < 2; ++v)
        *(frag8*)(oe + (size_t)on * K + ok + v * 8) = *(const frag8*)&tile[on][ok + v * 8];
}

// ---------- 256^2 8-phase GEMM, m201 stage schedule ----------
// A: bf16 [E][T][K] row-major; B: bf16 [E][N][K]; bias fp32 [E][N].
template <bool RELU_BF16>
__global__ __launch_bounds__(512, 2) void gemm256_kernel(
    const ushort* __restrict__ A, const ushort* __restrict__ Bm,
    const float* __restrict__ bias, void* __restrict__ Cout,
    const int K, const int N) {
    // [buf p: A tile 32K | B tile 32K] x2 buffers = 128 KiB
    __shared__ __align__(16) char lds[131072];

    const int bid = blockIdx.x;
    const int e = bid & 7;             // expert == XCD
    const int s = bid >> 3;
    const int m0 = (s & 7) * BM;       // M-fastest: B n-slab stays L2-hot
    const int n0 = (s >> 3) * BN;

    const ushort* Ae = A + (size_t)e * T * K + (size_t)m0 * K;
    const ushort* Be = Bm + (size_t)e * N * K + (size_t)n0 * K;

    const int tid = threadIdx.x;
    const int lane = tid & 63;
    const int wave = tid >> 6;
    const int wm = wave >> 2;          // 0..1
    const int wn = wave & 3;           // 0..3
    const int col = lane & 15;
    const int quad = lane >> 4;

    // staging: inverse-swizzled global source, linear LDS dest (rule #21)
    const int scc = (lane & 7) ^ (lane >> 3);
    const int srow = wave * 8 + (lane >> 3);
    const ushort* gA0 = Ae + (size_t)srow * K + scc * 8;
    const ushort* gB0 = Be + (size_t)srow * K + scc * 8;
    const int ldsA0 = wave * 1024;            // + p*65536 + h*16384 + i*8192
    const int ldsB0 = 32768 + wave * 1024;

    // frag-read swizzle: addr ^= ((row&7)<<4); row&7 == col&7 for every frag
    const int swz0 = ((quad ^ (col & 7)) << 4);
    const int swz1 = swz0 ^ 64;
    // interleaved ownership: rows wm*64+{0..63} and 128+wm*64+{0..63};
    //                        cols wn*32+{0..31} and 128+wn*32+{0..31}.
    const int aRow = (wm * 64 + col) * 128;   // byte base of A row-chunk0
    const int bRow = (wn * 32 + col) * 128;   // byte base of B col-chunk0

    const int NT = K / BK;

#define STAGE_A(p, h, kk) do {                                          \
        const ushort* g_ = gA0 + (size_t)(h) * 128 * K + (kk);          \
        char* l_ = lds + (p) * 65536 + ldsA0 + (h) * 16384;             \
        load16_to_lds(g_, l_);                                          \
        load16_to_lds(g_ + (size_t)64 * K, l_ + 8192);                  \
    } while (0)
#define STAGE_B(p, h, kk) do {                                          \
        const ushort* g_ = gB0 + (size_t)(h) * 128 * K + (kk);          \
        char* l_ = lds + (p) * 65536 + ldsB0 + (h) * 16384;             \
        load16_to_lds(g_, l_);                                          \
        load16_to_lds(g_ + (size_t)64 * K, l_ + 8192);                  \
    } while (0)
#define MFMA(a, b, c) __builtin_amdgcn_mfma_f32_16x16x32_bf16((a), (b), (c), 0, 0, 0)

    f32x4 acc[8][4] = {};
    frag8 A0f[8], A1f[8], Bf[4];   // Bf reused for col-chunk1 in ph3/ph4

    // ---- prologue: tile0 full + A-h0/A-h1/B-h0 of tile1 (14 loads) ----
    STAGE_A(0, 0, 0); STAGE_A(0, 1, 0);
    STAGE_B(0, 0, 0); STAGE_B(0, 1, 0);
    STAGE_A(1, 0, BK); STAGE_A(1, 1, BK); STAGE_B(1, 0, BK);
    asm volatile("s_waitcnt vmcnt(6)" ::: "memory");   // tile0 (oldest 8) landed
    __builtin_amdgcn_s_barrier();
    __builtin_amdgcn_sched_barrier(0);

#define TILE_ITER(u, p, pn) do {                                              \
        const int kB_ = ((u) + 1) * BK, kA_ = ((u) + 2) * BK;                 \
        const bool stB_ = (u) + 1 < NT, stA_ = (u) + 2 < NT;                  \
        const char* aT = lds + (p) * 65536 + aRow;                            \
        const char* bT = lds + (p) * 65536 + 32768 + bRow;                    \
        /* == ph1: (row-chunk0, col-chunk0) — 12 ds_read, consumption order */\
        A0f[0] = *(const frag8*)(aT + swz0);                                  \
        A0f[1] = *(const frag8*)(aT + swz1);                                  \
        Bf[0] = *(const frag8*)(bT + swz0);                                   \
        Bf[1] = *(const frag8*)(bT + swz1);                                   \
        Bf[2] = *(const frag8*)(bT + 2048 + swz0);                            \
        Bf[3] = *(const frag8*)(bT + 2048 + swz1);                            \
        _Pragma("unroll")                                                     \
        for (int i = 1; i < 4; ++i) {                                         \
            A0f[i * 2 + 0] = *(const frag8*)(aT + i * 2048 + swz0);           \
            A0f[i * 2 + 1] = *(const frag8*)(aT + i * 2048 + swz1);           \
        }                                                                     \
        if (stB_) STAGE_B(pn, 1, kB_);                                        \
        __builtin_amdgcn_s_barrier();                                         \
        __builtin_amdgcn_s_setprio(1);                                        \
        _Pragma("unroll")                                                     \
        for (int i = 0; i < 4; ++i)                                           \
            _Pragma("unroll")                                                 \
            for (int j = 0; j < 2; ++j) {                                     \
                acc[i][j] = MFMA(A0f[i * 2 + 0], Bf[j * 2 + 0], acc[i][j]);   \
                acc[i][j] = MFMA(A0f[i * 2 + 1], Bf[j * 2 + 1], acc[i][j]);   \
            }                                                                 \
        __builtin_amdgcn_s_setprio(0);                                        \
        __builtin_amdgcn_s_barrier();                                         \
        __builtin_amdgcn_sched_barrier(0);                                    \
        /* == ph2: (row-chunk1, col-chunk0) — 8 ds_read; A-h0 reads done == */\
        _Pragma("unroll")                                                     \
        for (int i = 0; i < 4; ++i) {                                         \
            A1f[i * 2 + 0] = *(const frag8*)(aT + 16384 + i * 2048 + swz0);   \
            A1f[i * 2 + 1] = *(const frag8*)(aT + 16384 + i * 2048 + swz1);   \
        }                                                                     \
        if (stA_) STAGE_A(p, 0, kA_);                                         \
        __builtin_amdgcn_s_barrier();                                         \
        __builtin_amdgcn_s_setprio(1);                                        \
        _Pragma("unroll")                                                     \
        for (int i = 0; i < 4; ++i)                                           \
            _Pragma("unroll")                                                 \
            for (int j = 0; j < 2; ++j) {                                     \
                acc[4 + i][j] = MFMA(A1f[i * 2 + 0], Bf[j * 2 + 0], acc[4 + i][j]); \
                acc[4 + i][j] = MFMA(A1f[i * 2 + 1], Bf[j * 2 + 1], acc[4 + i][j]); \
            }                                                                 \
        __builtin_amdgcn_s_setprio(0);                                        \
        __builtin_amdgcn_s_barrier();                                         \
        __builtin_amdgcn_sched_barrier(0);                                    \
        /* == ph3: (row-chunk1, col-chunk1) — 4 ds_read; A-h1 reads done == */\
        _Pragma("unroll")                                                     \
        for (int j = 0; j < 2; ++j) {                                         \
            Bf[j * 2 + 0] = *(const frag8*)(bT + 16384 + j * 2048 + swz0);    \
            Bf[j * 2 + 1] = *(const frag8*)(bT + 16384 + j * 2048 + swz1);    \
        }                                                                     \
        if (stA_) STAGE_A(p, 1, kA_);                                         \
        __builtin_amdgcn_s_barrier();                                         \
        __builtin_amdgcn_s_setprio(1);                                        \
        _Pragma("unroll")                                                     \
        for (int i = 0; i < 4; ++i)                                           \
            _Pragma("unroll")                                                 \
            for (int j = 0; j < 2; ++j) {                                     \
                acc[4 + i][2 + j] = MFMA(A1f[i * 2 + 0], Bf[j * 2 + 0], acc[4 + i][2 + j]); \
                acc[4 + i][2 + j] = MFMA(A1f[i * 2 + 1], Bf[j * 2 + 1], acc[4 + i][2 + j]); \
            }                                                                 \
        __builtin_amdgcn_s_setprio(0);                                        \
        __builtin_amdgcn_s_barrier();                                         \
        __builtin_amdgcn_sched_barrier(0);                                    \
        /* == ph4: (row-chunk0, col-chunk1) — 0 ds_read; B-h0 reads done == */\
        if (stA_) STAGE_B(p, 0, kA_);                                         \
        __builtin_amdgcn_s_setprio(1);                                        \
        _Pragma("unroll")                                                     \
        for (int i = 0; i < 4; ++i)                                           \
            _Pragma("unroll")                                                 \
            for (int j = 0; j < 2; ++j) {                                     \
                acc[i][2 + j] = MFMA(A0f[i * 2 + 0], Bf[j * 2 + 0], acc[i][2 + j]); \
                acc[i][2 + j] = MFMA(A0f[i * 2 + 1], Bf[j * 2 + 1], acc[i][2 + j]); \
            }                                                                 \
        __builtin_amdgcn_s_setprio(0);                                        \
        /* in flight after wait: A-h0/A-h1/B-h0 of tile u+2 = 3 halves */     \
        if (stA_) {                                                           \
            asm volatile("s_waitcnt vmcnt(6)" ::: "memory");                  \
        } else if (stB_) {                                                    \
            asm volatile("s_waitcnt vmcnt(0)" ::: "memory");                  \
        }                                                                     \
        __builtin_amdgcn_s_barrier();                                         \
        __builtin_amdgcn_sched_barrier(0);                                    \
    } while (0)

    for (int v = 0; v < NT / 2; ++v) {
        TILE_ITER(2 * v, 0, 1);
        TILE_ITER(2 * v + 1, 1, 0);
    }
#undef TILE_ITER

    // ---- epilogue: interleaved ownership mapping ----
    const float* be = bias + (size_t)e * N;
#pragma unroll
    for (int j = 0; j < 4; ++j) {
        const int nn = n0 + wn * 32 + (j & 1) * 16 + (j >> 1) * 128 + col;
        const float bv = be[nn];
#pragma unroll
        for (int i = 0; i < 8; ++i) {
            const int mb = m0 + wm * 64 + (i & 3) * 16 + (i >> 2) * 128 + quad * 4;
#pragma unroll
            for (int r = 0; r < 4; ++r) {
                float v = acc[i][j][r] + bv;
                if (RELU_BF16) {
                    v = v > 0.f ? v : 0.f;
                    ((ushort*)Cout)[(size_t)e * T * N + (size_t)(mb + r) * N + nn] = f2bf(v);
                } else {
                    ((float*)Cout)[(size_t)e * T * N + (size_t)(mb + r) * N + nn] = v;
                }
            }
        }
    }
#undef STAGE_A
#undef STAGE_B
#undef MFMA
}

// ---------- round-1 fallback (ws too small for prep regions) ----------

constexpr int FBM = 128, FBN = 128, FBK = 32;
constexpr int FLDK = FBK + 16;

__global__ __launch_bounds__(256) void fb_gemm1_kernel(
    const float* __restrict__ x, const float* __restrict__ w1,
    const float* __restrict__ b1, ushort* __restrict__ y1) {
    __shared__ __align__(16) ushort As[FBM * FLDK];
    __shared__ __align__(16) ushort Bs[FBN * FLDK];
    const int e = blockIdx.z, m0 = blockIdx.y * FBM, n0 = blockIdx.x * FBN;
    const float* xa = x + (size_t)e * T * D + (size_t)m0 * D;
    const float* wb = w1 + (size_t)e * D * H;
    const int tid = threadIdx.x, lane = tid & 63, wave = tid >> 6;
    const int waveM = (wave >> 1) * 64, waveN = (wave & 1) * 64;
    const int col = lane & 15, quad = lane >> 4;
    const int ar = tid >> 3, ak = (tid & 7) * 4;
    const int bn = tid & 127, bk = (tid >> 7) * 16;
    f32x4 acc[4][4] = {};
    for (int k0 = 0; k0 < D; k0 += FBK) {
#pragma unroll
        for (int p = 0; p < 4; ++p) {
            const float4 v = *(const float4*)(xa + (size_t)(ar + 32 * p) * D + k0 + ak);
            ushort* dst = &As[(ar + 32 * p) * FLDK + ak];
            dst[0] = f2bf(v.x); dst[1] = f2bf(v.y); dst[2] = f2bf(v.z); dst[3] = f2bf(v.w);
        }
        {
            ushort tmp[16];
#pragma unroll
            for (int j = 0; j < 16; ++j)
                tmp[j] = f2bf(wb[(size_t)(k0 + bk + j) * H + n0 + bn]);
            ushort* dst = &Bs[bn * FLDK + bk];
#pragma unroll
            for (int j = 0; j < 16; ++j) dst[j] = tmp[j];
        }
        __syncthreads();
        frag8 af[4], bf[4];
#pragma unroll
        for (int i = 0; i < 4; ++i) {
            af[i] = *(const frag8*)&As[(waveM + i * 16 + col) * FLDK + quad * 8];
            bf[i] = *(const frag8*)&Bs[(waveN + i * 16 + col) * FLDK + quad * 8];
        }
#pragma unroll
        for (int i = 0; i < 4; ++i)
#pragma unroll
            for (int j = 0; j < 4; ++j)
                acc[i][j] = __builtin_amdgcn_mfma_f32_16x16x32_bf16(af[i], bf[j], acc[i][j], 0, 0, 0);
        __syncthreads();
    }
    const float* be = b1 + (size_t)e * H;
    ushort* ye = y1 + (size_t)e * T * H;
#pragma unroll
    for (int j = 0; j < 4; ++j) {
        const int n = n0 + waveN + j * 16 + col;
        const float bias = be[n];
#pragma unroll
        for (int i = 0; i < 4; ++i) {
            const int mb = m0 + waveM + i * 16 + quad * 4;
#pragma unroll
            for (int r = 0; r < 4; ++r) {
                float v = acc[i][j][r] + bias;
                v = v > 0.f ? v : 0.f;
                ye[(size_t)(mb + r) * H + n] = f2bf(v);
            }
        }
    }
}

__global__ __launch_bounds__(256) void fb_gemm2_kernel(
    const ushort* __restrict__ y1, const float* __restrict__ w2,
    const float* __restrict__ b2, float* __restrict__ out) {
    __shared__ __align__(16) ushort As[FBM * FLDK];
    __shared__ __align__(16) ushort Bs[FBN * FLDK];
    const int e = blockIdx.z, m0 = blockIdx.y * FBM, n0 = blockIdx.x * FBN;
    const ushort* ya = y1 + (size_t)e * T * H + (size_t)m0 * H;
    const float* wb = w2 + (size_t)e * H * D;
    const int tid = threadIdx.x, lane = tid & 63, wave = tid >> 6;
    const int waveM = (wave >> 1) * 64, waveN = (wave & 1) * 64;
    const int col = lane & 15, quad = lane >> 4;
    const int ar = tid >> 2, ak = (tid & 3) * 8;
    const int bn = tid & 127, bk = (tid >> 7) * 16;
    f32x4 acc[4][4] = {};
    for (int k0 = 0; k0 < H; k0 += FBK) {
#pragma unroll
        for (int p = 0; p < 2; ++p)
            *(frag8*)&As[(ar + 64 * p) * FLDK + ak] =
                *(const frag8*)(ya + (size_t)(ar + 64 * p) * H + k0 + ak);
        {
            ushort tmp[16];
#pragma unroll
            for (int j = 0; j < 16; ++j)
                tmp[j] = f2bf(wb[(size_t)(k0 + bk + j) * D + n0 + bn]);
            ushort* dst = &Bs[bn * FLDK + bk];
#pragma unroll
            for (int j = 0; j < 16; ++j) dst[j] = tmp[j];
        }
        __syncthreads();
        frag8 af[4], bf[4];
#pragma unroll
        for (int i = 0; i < 4; ++i) {
            af[i] = *(const frag8*)&As[(waveM + i * 16 + col) * FLDK + quad * 8];
            bf[i] = *(const frag8*)&Bs[(waveN + i * 16 + col) * FLDK + quad * 8];
        }
#pragma unroll
        for (int i = 0; i < 4; ++i)
#pragma unroll
            for (int j = 0; j < 4; ++j)
                acc[i][j] = __builtin_amdgcn_mfma_f32_16x16x32_bf16(af[i], bf[j], acc[i][j], 0, 0, 0);
        __syncthreads();
    }
    const float* be = b2 + (size_t)e * D;
    float* oe = out + (size_t)e * T * D;
#pragma unroll
    for (int j = 0; j < 4; ++j) {
        const int n = n0 + waveN + j * 16 + col;
        const float bias = be[n];
#pragma unroll
        for (int i = 0; i < 4; ++i) {
            const int mb = m0 + waveM + i * 16 + quad * 4;
#pragma unroll
            for (int r = 0; r < 4; ++r)
                oe[(size_t)(mb + r) * D + n] = acc[i][j][r] + bias;
        }
    }
}

extern "C" void kernel_launch(void* const* d_in, const int* in_sizes, int n_in,
                              void* d_out, int out_size, void* d_ws, size_t ws_size,
                              hipStream_t stream) {
    const float* x  = (const float*)d_in[0];   // [E,T,D]
    const float* w1 = (const float*)d_in[1];   // [E,D,H]
    const float* b1 = (const float*)d_in[2];   // [E,1,H]
    const float* w2 = (const float*)d_in[3];   // [E,H,D]
    const float* b2 = (const float*)d_in[4];   // [E,1,D]
    float* out = (float*)d_out;                // [E,T,D]

    const size_t y1_bytes = (size_t)E * T * H * 2;  // 128 MB
    const size_t wt_bytes = (size_t)E * D * H * 2;  //  64 MB (shared w1t/w2t)
    const size_t xb_bytes = (size_t)E * T * D * 2;  //  32 MB
    const size_t need = y1_bytes + wt_bytes + xb_bytes;  // 224 MB

    if (ws_size >= need) {
        ushort* y1 = (ushort*)d_ws;
        ushort* wt = (ushort*)((char*)d_ws + y1_bytes);
        ushort* xb = (ushort*)((char*)d_ws + y1_bytes + wt_bytes);

        // 1. x -> bf16
        cvt_bf16_kernel<<<(E * T * D) / (256 * 4), 256, 0, stream>>>(x, xb);
        // 2. w1 [E][D][H] -> wt [E][H][D] bf16
        transpose_cvt_kernel<<<dim3(H / 64, D / 64, E), 256, 0, stream>>>(w1, wt, D, H);
        // 3. gemm1: y1 = relu(xb @ w1 + b1), bf16   (8x8x16 = 1024 blocks)
        gemm256_kernel<true><<<E * (T / BM) * (H / BN), 512, 0, stream>>>(xb, wt, b1, y1, D, H);
        // 4. w2 [E][H][D] -> wt [E][D][H] bf16 (region reuse)
        transpose_cvt_kernel<<<dim3(D / 64, H / 64, E), 256, 0, stream>>>(w2, wt, H, D);
        // 5. gemm2: out = y1 @ w2 + b2, fp32        (8x8x4 = 256 blocks)
        gemm256_kernel<false><<<E * (T / BM) * (D / BN), 512, 0, stream>>>(y1, wt, b2, out, H, D);
    } else {
        ushort* y1 = (ushort*)d_ws;
        fb_gemm1_kernel<<<dim3(H / FBN, T / FBM, E), 256, 0, stream>>>(x, w1, b1, y1);
        fb_gemm2_kernel<<<dim3(D / FBN, T / FBM, E), 256, 0, stream>>>(y1, w2, b2, out);
    }
}

// Round 4
// 596.728 us; speedup vs baseline: 1.2999x; 1.0059x over previous
//
#include <hip/hip_runtime.h>
#include <hip/hip_bf16.h>
#include <stdint.h>

// Batched expert FFN: out = relu(x @ w1 + b1) @ w2 + b2
// E=8, T=2048, D=1024, H=4096, fp32 in/out, bf16 MFMA compute (fp32 accum).
//
// Round 7: n-fastest rasterization within each expert. Rounds 2/3 showed the
// GEMM loop is invariant under schedule changes and sustains exactly ~7 TB/s
// of stage traffic (64 KB/CU/K-tile @ 5775 cy) with ~zero L2 reuse (1 GB
// L2-miss per gemm = full per-block compulsory). m-fastest cohorts (8m x 4n
// per XCD) need 6 MB resident vs 4 MB L2 -> thrash. n-fastest cohorts
// (2m x 16n) pin only the 2 A-panels (1 MB, 16x reuse) and hit B within a
// fresh 0.5 MB window; k-slices stay aligned across the cohort.

using frag8 = __attribute__((ext_vector_type(8))) short;   // 8 bf16 (4 VGPRs)
using f32x4 = __attribute__((ext_vector_type(4))) float;   // MFMA C/D

constexpr int E = 8, T = 2048, D = 1024, H = 4096;
constexpr int BM = 256, BN = 256, BK = 64;

__device__ __forceinline__ ushort f2bf(float f) {
    union { float f; uint32_t u; } v; v.f = f;
    return (ushort)((v.u + 0x7FFFu + ((v.u >> 16) & 1u)) >> 16);  // RTNE
}

__device__ __forceinline__ void load16_to_lds(const void* g, void* l) {
    __builtin_amdgcn_global_load_lds(
        (const __attribute__((address_space(1))) uint32_t*)g,
        (__attribute__((address_space(3))) uint32_t*)l, 16, 0, 0);
}

// ---------- prep kernels ----------

__global__ __launch_bounds__(256) void cvt_bf16_kernel(
    const float* __restrict__ in, ushort* __restrict__ out) {
    const size_t i = ((size_t)blockIdx.x * 256 + threadIdx.x) * 4;
    const float4 v = *(const float4*)(in + i);
    ushort4 o;
    o.x = f2bf(v.x); o.y = f2bf(v.y); o.z = f2bf(v.z); o.w = f2bf(v.w);
    *(ushort4*)(out + i) = o;
}

// in[e][K][N] fp32 -> out[e][N][K] bf16; 64x64 tiles, coalesced both sides.
__global__ __launch_bounds__(256) void transpose_cvt_kernel(
    const float* __restrict__ in, ushort* __restrict__ out, int K, int N) {
    __shared__ __align__(16) ushort tile[64][72];
    const int e = blockIdx.z;
    const int k0 = blockIdx.y * 64, n0 = blockIdx.x * 64;
    const float* ie = in + (size_t)e * K * N + (size_t)k0 * N + n0;
    ushort* oe = out + (size_t)e * N * K + (size_t)n0 * K + k0;
    const int t = threadIdx.x;
    const int lc = (t & 15) * 4;       // col (n) base
    const int lr = (t >> 4) * 2;       // row (k) base, even
#pragma unroll
    for (int pass = 0; pass < 2; ++pass) {
        const int r = lr + pass * 32;
        const float4 f0 = *(const float4*)(ie + (size_t)r * N + lc);
        const float4 f1 = *(const float4*)(ie + (size_t)(r + 1) * N + lc);
        const float x0[4] = {f0.x, f0.y, f0.z, f0.w};
        const float x1[4] = {f1.x, f1.y, f1.z, f1.w};
#pragma unroll
        for (int i = 0; i < 4; ++i) {
            ushort2 p; p.x = f2bf(x0[i]); p.y = f2bf(x1[i]);
            *(ushort2*)&tile[lc + i][r] = p;   // 4B-aligned (r even)
        }
    }
    __syncthreads();
    const int on = t >> 2;
    const int ok = (t & 3) * 16;
#pragma unroll
    for (int v = 0; v < 2; ++v)
        *(frag8*)(oe + (size_t)on * K + ok + v * 8) = *(const frag8*)&tile[on][ok + v * 8];
}

// ---------- 256^2 8-phase GEMM, m201 stage schedule ----------
// A: bf16 [E][T][K] row-major; B: bf16 [E][N][K]; bias fp32 [E][N].
template <bool RELU_BF16>
__global__ __launch_bounds__(512, 2) void gemm256_kernel(
    const ushort* __restrict__ A, const ushort* __restrict__ Bm,
    const float* __restrict__ bias, void* __restrict__ Cout,
    const int K, const int N) {
    // [buf p: A tile 32K | B tile 32K] x2 buffers = 128 KiB
    __shared__ __align__(16) char lds[131072];

    const int bid = blockIdx.x;
    const int e = bid & 7;             // expert == XCD
    const int s = bid >> 3;
    // n-fastest within expert: cohort of 32 resident blocks per XCD spans
    // few m (A pinned in L2, 16x reuse) x many n (B hit within fresh window).
    const int nb = N >> 8;             // n-blocks per expert (pow2: 16 or 4)
    const int n0 = (s & (nb - 1)) * BN;
    const int m0 = (s >> __builtin_ctz(nb)) * BM;

    const ushort* Ae = A + (size_t)e * T * K + (size_t)m0 * K;
    const ushort* Be = Bm + (size_t)e * N * K + (size_t)n0 * K;

    const int tid = threadIdx.x;
    const int lane = tid & 63;
    const int wave = tid >> 6;
    const int wm = wave >> 2;          // 0..1
    const int wn = wave & 3;           // 0..3
    const int col = lane & 15;
    const int quad = lane >> 4;

    // staging: inverse-swizzled global source, linear LDS dest (rule #21)
    const int scc = (lane & 7) ^ (lane >> 3);
    const int srow = wave * 8 + (lane >> 3);
    const ushort* gA0 = Ae + (size_t)srow * K + scc * 8;
    const ushort* gB0 = Be + (size_t)srow * K + scc * 8;
    const int ldsA0 = wave * 1024;            // + p*65536 + h*16384 + i*8192
    const int ldsB0 = 32768 + wave * 1024;

    // frag-read swizzle: addr ^= ((row&7)<<4); row&7 == col&7 for every frag
    const int swz0 = ((quad ^ (col & 7)) << 4);
    const int swz1 = swz0 ^ 64;
    // interleaved ownership: rows wm*64+{0..63} and 128+wm*64+{0..63};
    //                        cols wn*32+{0..31} and 128+wn*32+{0..31}.
    const int aRow = (wm * 64 + col) * 128;   // byte base of A row-chunk0
    const int bRow = (wn * 32 + col) * 128;   // byte base of B col-chunk0

    const int NT = K / BK;

#define STAGE_A(p, h, kk) do {                                          \
        const ushort* g_ = gA0 + (size_t)(h) * 128 * K + (kk);          \
        char* l_ = lds + (p) * 65536 + ldsA0 + (h) * 16384;             \
        load16_to_lds(g_, l_);                                          \
        load16_to_lds(g_ + (size_t)64 * K, l_ + 8192);                  \
    } while (0)
#define STAGE_B(p, h, kk) do {                                          \
        const ushort* g_ = gB0 + (size_t)(h) * 128 * K + (kk);          \
        char* l_ = lds + (p) * 65536 + ldsB0 + (h) * 16384;             \
        load16_to_lds(g_, l_);                                          \
        load16_to_lds(g_ + (size_t)64 * K, l_ + 8192);                  \
    } while (0)
#define MFMA(a, b, c) __builtin_amdgcn_mfma_f32_16x16x32_bf16((a), (b), (c), 0, 0, 0)

    f32x4 acc[8][4] = {};
    frag8 A0f[8], A1f[8], Bf[4];   // Bf reused for col-chunk1 in ph3/ph4

    // ---- prologue: tile0 full + A-h0/A-h1/B-h0 of tile1 (14 loads) ----
    STAGE_A(0, 0, 0); STAGE_A(0, 1, 0);
    STAGE_B(0, 0, 0); STAGE_B(0, 1, 0);
    STAGE_A(1, 0, BK); STAGE_A(1, 1, BK); STAGE_B(1, 0, BK);
    asm volatile("s_waitcnt vmcnt(6)" ::: "memory");   // tile0 (oldest 8) landed
    __builtin_amdgcn_s_barrier();
    __builtin_amdgcn_sched_barrier(0);

#define TILE_ITER(u, p, pn) do {                                              \
        const int kB_ = ((u) + 1) * BK, kA_ = ((u) + 2) * BK;                 \
        const bool stB_ = (u) + 1 < NT, stA_ = (u) + 2 < NT;                  \
        const char* aT = lds + (p) * 65536 + aRow;                            \
        const char* bT = lds + (p) * 65536 + 32768 + bRow;                    \
        /* == ph1: (row-chunk0, col-chunk0) — 12 ds_read, consumption order */\
        A0f[0] = *(const frag8*)(aT + swz0);                                  \
        A0f[1] = *(const frag8*)(aT + swz1);                                  \
        Bf[0] = *(const frag8*)(bT + swz0);                                   \
        Bf[1] = *(const frag8*)(bT + swz1);                                   \
        Bf[2] = *(const frag8*)(bT + 2048 + swz0);                            \
        Bf[3] = *(const frag8*)(bT + 2048 + swz1);                            \
        _Pragma("unroll")                                                     \
        for (int i = 1; i < 4; ++i) {                                         \
            A0f[i * 2 + 0] = *(const frag8*)(aT + i * 2048 + swz0);           \
            A0f[i * 2 + 1] = *(const frag8*)(aT + i * 2048 + swz1);           \
        }                                                                     \
        if (stB_) STAGE_B(pn, 1, kB_);                                        \
        __builtin_amdgcn_s_barrier();                                         \
        __builtin_amdgcn_s_setprio(1);                                        \
        _Pragma("unroll")                                                     \
        for (int i = 0; i < 4; ++i)                                           \
            _Pragma("unroll")                                                 \
            for (int j = 0; j < 2; ++j) {                                     \
                acc[i][j] = MFMA(A0f[i * 2 + 0], Bf[j * 2 + 0], acc[i][j]);   \
                acc[i][j] = MFMA(A0f[i * 2 + 1], Bf[j * 2 + 1], acc[i][j]);   \
            }                                                                 \
        __builtin_amdgcn_s_setprio(0);                                        \
        __builtin_amdgcn_s_barrier();                                         \
        __builtin_amdgcn_sched_barrier(0);                                    \
        /* == ph2: (row-chunk1, col-chunk0) — 8 ds_read; A-h0 reads done == */\
        _Pragma("unroll")                                                     \
        for (int i = 0; i < 4; ++i) {                                         \
            A1f[i * 2 + 0] = *(const frag8*)(aT + 16384 + i * 2048 + swz0);   \
            A1f[i * 2 + 1] = *(const frag8*)(aT + 16384 + i * 2048 + swz1);   \
        }                                                                     \
        if (stA_) STAGE_A(p, 0, kA_);                                         \
        __builtin_amdgcn_s_barrier();                                         \
        __builtin_amdgcn_s_setprio(1);                                        \
        _Pragma("unroll")                                                     \
        for (int i = 0; i < 4; ++i)                                           \
            _Pragma("unroll")                                                 \
            for (int j = 0; j < 2; ++j) {                                     \
                acc[4 + i][j] = MFMA(A1f[i * 2 + 0], Bf[j * 2 + 0], acc[4 + i][j]); \
                acc[4 + i][j] = MFMA(A1f[i * 2 + 1], Bf[j * 2 + 1], acc[4 + i][j]); \
            }                                                                 \
        __builtin_amdgcn_s_setprio(0);                                        \
        __builtin_amdgcn_s_barrier();                                         \
        __builtin_amdgcn_sched_barrier(0);                                    \
        /* == ph3: (row-chunk1, col-chunk1) — 4 ds_read; A-h1 reads done == */\
        _Pragma("unroll")                                                     \
        for (int j = 0; j < 2; ++j) {                                         \
            Bf[j * 2 + 0] = *(const frag8*)(bT + 16384 + j * 2048 + swz0);    \
            Bf[j * 2 + 1] = *(const frag8*)(bT + 16384 + j * 2048 + swz1);    \
        }                                                                     \
        if (stA_) STAGE_A(p, 1, kA_);                                         \
        __builtin_amdgcn_s_barrier();                                         \
        __builtin_amdgcn_s_setprio(1);                                        \
        _Pragma("unroll")                                                     \
        for (int i = 0; i < 4; ++i)                                           \
            _Pragma("unroll")                                                 \
            for (int j = 0; j < 2; ++j) {                                     \
                acc[4 + i][2 + j] = MFMA(A1f[i * 2 + 0], Bf[j * 2 + 0], acc[4 + i][2 + j]); \
                acc[4 + i][2 + j] = MFMA(A1f[i * 2 + 1], Bf[j * 2 + 1], acc[4 + i][2 + j]); \
            }                                                                 \
        __builtin_amdgcn_s_setprio(0);                                        \
        __builtin_amdgcn_s_barrier();                                         \
        __builtin_amdgcn_sched_barrier(0);                                    \
        /* == ph4: (row-chunk0, col-chunk1) — 0 ds_read; B-h0 reads done == */\
        if (stA_) STAGE_B(p, 0, kA_);                                         \
        __builtin_amdgcn_s_setprio(1);                                        \
        _Pragma("unroll")                                                     \
        for (int i = 0; i < 4; ++i)                                           \
            _Pragma("unroll")                                                 \
            for (int j = 0; j < 2; ++j) {                                     \
                acc[i][2 + j] = MFMA(A0f[i * 2 + 0], Bf[j * 2 + 0], acc[i][2 + j]); \
                acc[i][2 + j] = MFMA(A0f[i * 2 + 1], Bf[j * 2 + 1], acc[i][2 + j]); \
            }                                                                 \
        __builtin_amdgcn_s_setprio(0);                                        \
        /* in flight after wait: A-h0/A-h1/B-h0 of tile u+2 = 3 halves */     \
        if (stA_) {                                                           \
            asm volatile("s_waitcnt vmcnt(6)" ::: "memory");                  \
        } else if (stB_) {                                                    \
            asm volatile("s_waitcnt vmcnt(0)" ::: "memory");                  \
        }                                                                     \
        __builtin_amdgcn_s_barrier();                                         \
        __builtin_amdgcn_sched_barrier(0);                                    \
    } while (0)

    for (int v = 0; v < NT / 2; ++v) {
        TILE_ITER(2 * v, 0, 1);
        TILE_ITER(2 * v + 1, 1, 0);
    }
#undef TILE_ITER

    // ---- epilogue: interleaved ownership mapping ----
    const float* be = bias + (size_t)e * N;
#pragma unroll
    for (int j = 0; j < 4; ++j) {
        const int nn = n0 + wn * 32 + (j & 1) * 16 + (j >> 1) * 128 + col;
        const float bv = be[nn];
#pragma unroll
        for (int i = 0; i < 8; ++i) {
            const int mb = m0 + wm * 64 + (i & 3) * 16 + (i >> 2) * 128 + quad * 4;
#pragma unroll
            for (int r = 0; r < 4; ++r) {
                float v = acc[i][j][r] + bv;
                if (RELU_BF16) {
                    v = v > 0.f ? v : 0.f;
                    ((ushort*)Cout)[(size_t)e * T * N + (size_t)(mb + r) * N + nn] = f2bf(v);
                } else {
                    ((float*)Cout)[(size_t)e * T * N + (size_t)(mb + r) * N + nn] = v;
                }
            }
        }
    }
#undef STAGE_A
#undef STAGE_B
#undef MFMA
}

// ---------- round-1 fallback (ws too small for prep regions) ----------

constexpr int FBM = 128, FBN = 128, FBK = 32;
constexpr int FLDK = FBK + 16;

__global__ __launch_bounds__(256) void fb_gemm1_kernel(
    const float* __restrict__ x, const float* __restrict__ w1,
    const float* __restrict__ b1, ushort* __restrict__ y1) {
    __shared__ __align__(16) ushort As[FBM * FLDK];
    __shared__ __align__(16) ushort Bs[FBN * FLDK];
    const int e = blockIdx.z, m0 = blockIdx.y * FBM, n0 = blockIdx.x * FBN;
    const float* xa = x + (size_t)e * T * D + (size_t)m0 * D;
    const float* wb = w1 + (size_t)e * D * H;
    const int tid = threadIdx.x, lane = tid & 63, wave = tid >> 6;
    const int waveM = (wave >> 1) * 64, waveN = (wave & 1) * 64;
    const int col = lane & 15, quad = lane >> 4;
    const int ar = tid >> 3, ak = (tid & 7) * 4;
    const int bn = tid & 127, bk = (tid >> 7) * 16;
    f32x4 acc[4][4] = {};
    for (int k0 = 0; k0 < D; k0 += FBK) {
#pragma unroll
        for (int p = 0; p < 4; ++p) {
            const float4 v = *(const float4*)(xa + (size_t)(ar + 32 * p) * D + k0 + ak);
            ushort* dst = &As[(ar + 32 * p) * FLDK + ak];
            dst[0] = f2bf(v.x); dst[1] = f2bf(v.y); dst[2] = f2bf(v.z); dst[3] = f2bf(v.w);
        }
        {
            ushort tmp[16];
#pragma unroll
            for (int j = 0; j < 16; ++j)
                tmp[j] = f2bf(wb[(size_t)(k0 + bk + j) * H + n0 + bn]);
            ushort* dst = &Bs[bn * FLDK + bk];
#pragma unroll
            for (int j = 0; j < 16; ++j) dst[j] = tmp[j];
        }
        __syncthreads();
        frag8 af[4], bf[4];
#pragma unroll
        for (int i = 0; i < 4; ++i) {
            af[i] = *(const frag8*)&As[(waveM + i * 16 + col) * FLDK + quad * 8];
            bf[i] = *(const frag8*)&Bs[(waveN + i * 16 + col) * FLDK + quad * 8];
        }
#pragma unroll
        for (int i = 0; i < 4; ++i)
#pragma unroll
            for (int j = 0; j < 4; ++j)
                acc[i][j] = __builtin_amdgcn_mfma_f32_16x16x32_bf16(af[i], bf[j], acc[i][j], 0, 0, 0);
        __syncthreads();
    }
    const float* be = b1 + (size_t)e * H;
    ushort* ye = y1 + (size_t)e * T * H;
#pragma unroll
    for (int j = 0; j < 4; ++j) {
        const int n = n0 + waveN + j * 16 + col;
        const float bias = be[n];
#pragma unroll
        for (int i = 0; i < 4; ++i) {
            const int mb = m0 + waveM + i * 16 + quad * 4;
#pragma unroll
            for (int r = 0; r < 4; ++r) {
                float v = acc[i][j][r] + bias;
                v = v > 0.f ? v : 0.f;
                ye[(size_t)(mb + r) * H + n] = f2bf(v);
            }
        }
    }
}

__global__ __launch_bounds__(256) void fb_gemm2_kernel(
    const ushort* __restrict__ y1, const float* __restrict__ w2,
    const float* __restrict__ b2, float* __restrict__ out) {
    __shared__ __align__(16) ushort As[FBM * FLDK];
    __shared__ __align__(16) ushort Bs[FBN * FLDK];
    const int e = blockIdx.z, m0 = blockIdx.y * FBM, n0 = blockIdx.x * FBN;
    const ushort* ya = y1 + (size_t)e * T * H + (size_t)m0 * H;
    const float* wb = w2 + (size_t)e * H * D;
    const int tid = threadIdx.x, lane = tid & 63, wave = tid >> 6;
    const int waveM = (wave >> 1) * 64, waveN = (wave & 1) * 64;
    const int col = lane & 15, quad = lane >> 4;
    const int ar = tid >> 2, ak = (tid & 3) * 8;
    const int bn = tid & 127, bk = (tid >> 7) * 16;
    f32x4 acc[4][4] = {};
    for (int k0 = 0; k0 < H; k0 += FBK) {
#pragma unroll
        for (int p = 0; p < 2; ++p)
            *(frag8*)&As[(ar + 64 * p) * FLDK + ak] =
                *(const frag8*)(ya + (size_t)(ar + 64 * p) * H + k0 + ak);
        {
            ushort tmp[16];
#pragma unroll
            for (int j = 0; j < 16; ++j)
                tmp[j] = f2bf(wb[(size_t)(k0 + bk + j) * D + n0 + bn]);
            ushort* dst = &Bs[bn * FLDK + bk];
#pragma unroll
            for (int j = 0; j < 16; ++j) dst[j] = tmp[j];
        }
        __syncthreads();
        frag8 af[4], bf[4];
#pragma unroll
        for (int i = 0; i < 4; ++i) {
            af[i] = *(const frag8*)&As[(waveM + i * 16 + col) * FLDK + quad * 8];
            bf[i] = *(const frag8*)&Bs[(waveN + i * 16 + col) * FLDK + quad * 8];
        }
#pragma unroll
        for (int i = 0; i < 4; ++i)
#pragma unroll
            for (int j = 0; j < 4; ++j)
                acc[i][j] = __builtin_amdgcn_mfma_f32_16x16x32_bf16(af[i], bf[j], acc[i][j], 0, 0, 0);
        __syncthreads();
    }
    const float* be = b2 + (size_t)e * D;
    float* oe = out + (size_t)e * T * D;
#pragma unroll
    for (int j = 0; j < 4; ++j) {
        const int n = n0 + waveN + j * 16 + col;
        const float bias = be[n];
#pragma unroll
        for (int i = 0; i < 4; ++i) {
            const int mb = m0 + waveM + i * 16 + quad * 4;
#pragma unroll
            for (int r = 0; r < 4; ++r)
                oe[(size_t)(mb + r) * D + n] = acc[i][j][r] + bias;
        }
    }
}

extern "C" void kernel_launch(void* const* d_in, const int* in_sizes, int n_in,
                              void* d_out, int out_size, void* d_ws, size_t ws_size,
                              hipStream_t stream) {
    const float* x  = (const float*)d_in[0];   // [E,T,D]
    const float* w1 = (const float*)d_in[1];   // [E,D,H]
    const float* b1 = (const float*)d_in[2];   // [E,1,H]
    const float* w2 = (const float*)d_in[3];   // [E,H,D]
    const float* b2 = (const float*)d_in[4];   // [E,1,D]
    float* out = (float*)d_out;                // [E,T,D]

    const size_t y1_bytes = (size_t)E * T * H * 2;  // 128 MB
    const size_t wt_bytes = (size_t)E * D * H * 2;  //  64 MB (shared w1t/w2t)
    const size_t xb_bytes = (size_t)E * T * D * 2;  //  32 MB
    const size_t need = y1_bytes + wt_bytes + xb_bytes;  // 224 MB

    if (ws_size >= need) {
        ushort* y1 = (ushort*)d_ws;
        ushort* wt = (ushort*)((char*)d_ws + y1_bytes);
        ushort* xb = (ushort*)((char*)d_ws + y1_bytes + wt_bytes);

        // 1. x -> bf16
        cvt_bf16_kernel<<<(E * T * D) / (256 * 4), 256, 0, stream>>>(x, xb);
        // 2. w1 [E][D][H] -> wt [E][H][D] bf16
        transpose_cvt_kernel<<<dim3(H / 64, D / 64, E), 256, 0, stream>>>(w1, wt, D, H);
        // 3. gemm1: y1 = relu(xb @ w1 + b1), bf16   (8x8x16 = 1024 blocks)
        gemm256_kernel<true><<<E * (T / BM) * (H / BN), 512, 0, stream>>>(xb, wt, b1, y1, D, H);
        // 4. w2 [E][H][D] -> wt [E][D][H] bf16 (region reuse)
        transpose_cvt_kernel<<<dim3(D / 64, H / 64, E), 256, 0, stream>>>(w2, wt, H, D);
        // 5. gemm2: out = y1 @ w2 + b2, fp32        (8x8x4 = 256 blocks)
        gemm256_kernel<false><<<E * (T / BM) * (D / BN), 512, 0, stream>>>(y1, wt, b2, out, H, D);
    } else {
        ushort* y1 = (ushort*)d_ws;
        fb_gemm1_kernel<<<dim3(H / FBN, T / FBM, E), 256, 0, stream>>>(x, w1, b1, y1);
        fb_gemm2_kernel<<<dim3(D / FBN, T / FBM, E), 256, 0, stream>>>(y1, w2, b2, out);
    }
}

// Round 5
// 570.143 us; speedup vs baseline: 1.3606x; 1.0466x over previous
//
#include <hip/hip_runtime.h>
#include <hip/hip_bf16.h>
#include <stdint.h>

// Batched expert FFN: out = relu(x @ w1 + b1) @ w2 + b2
// E=8, T=2048, D=1024, H=4096, fp32 in/out, bf16 MFMA compute (fp32 accum).
//
// Round 8: explicit fragment pipelining. Rounds 2-4 proved the loop invariant
// (153 us, MfmaUtil 38%) under schedule/raster changes because every phase
// read its OWN MFMA operands across a barrier -> per-phase LDS-drain stall
// serialized with MFMA (5730 cy/K-tile vs 2483 MFMA floor). Now each phase's
// operands are read ONE PHASE EARLY (A1f during ph1, B-h1 during ph2 after
// q10 frees Bf via WAR), so ph2-ph4 MFMA clusters start with operands already
// in flight/landed. Register-neutral (same A0f/A1f/Bf set). One barrier per
// phase (4/K-tile, was 8). Stage slots + vmcnt(6) discipline unchanged
// (proven rounds 2-4).

using frag8 = __attribute__((ext_vector_type(8))) short;   // 8 bf16 (4 VGPRs)
using f32x4 = __attribute__((ext_vector_type(4))) float;   // MFMA C/D

constexpr int E = 8, T = 2048, D = 1024, H = 4096;
constexpr int BM = 256, BN = 256, BK = 64;

__device__ __forceinline__ ushort f2bf(float f) {
    union { float f; uint32_t u; } v; v.f = f;
    return (ushort)((v.u + 0x7FFFu + ((v.u >> 16) & 1u)) >> 16);  // RTNE
}

__device__ __forceinline__ void load16_to_lds(const void* g, void* l) {
    __builtin_amdgcn_global_load_lds(
        (const __attribute__((address_space(1))) uint32_t*)g,
        (__attribute__((address_space(3))) uint32_t*)l, 16, 0, 0);
}

// ---------- prep kernels (unchanged) ----------

__global__ __launch_bounds__(256) void cvt_bf16_kernel(
    const float* __restrict__ in, ushort* __restrict__ out) {
    const size_t i = ((size_t)blockIdx.x * 256 + threadIdx.x) * 4;
    const float4 v = *(const float4*)(in + i);
    ushort4 o;
    o.x = f2bf(v.x); o.y = f2bf(v.y); o.z = f2bf(v.z); o.w = f2bf(v.w);
    *(ushort4*)(out + i) = o;
}

// in[e][K][N] fp32 -> out[e][N][K] bf16; 64x64 tiles, coalesced both sides.
__global__ __launch_bounds__(256) void transpose_cvt_kernel(
    const float* __restrict__ in, ushort* __restrict__ out, int K, int N) {
    __shared__ __align__(16) ushort tile[64][72];
    const int e = blockIdx.z;
    const int k0 = blockIdx.y * 64, n0 = blockIdx.x * 64;
    const float* ie = in + (size_t)e * K * N + (size_t)k0 * N + n0;
    ushort* oe = out + (size_t)e * N * K + (size_t)n0 * K + k0;
    const int t = threadIdx.x;
    const int lc = (t & 15) * 4;       // col (n) base
    const int lr = (t >> 4) * 2;       // row (k) base, even
#pragma unroll
    for (int pass = 0; pass < 2; ++pass) {
        const int r = lr + pass * 32;
        const float4 f0 = *(const float4*)(ie + (size_t)r * N + lc);
        const float4 f1 = *(const float4*)(ie + (size_t)(r + 1) * N + lc);
        const float x0[4] = {f0.x, f0.y, f0.z, f0.w};
        const float x1[4] = {f1.x, f1.y, f1.z, f1.w};
#pragma unroll
        for (int i = 0; i < 4; ++i) {
            ushort2 p; p.x = f2bf(x0[i]); p.y = f2bf(x1[i]);
            *(ushort2*)&tile[lc + i][r] = p;   // 4B-aligned (r even)
        }
    }
    __syncthreads();
    const int on = t >> 2;
    const int ok = (t & 3) * 16;
#pragma unroll
    for (int v = 0; v < 2; ++v)
        *(frag8*)(oe + (size_t)on * K + ok + v * 8) = *(const frag8*)&tile[on][ok + v * 8];
}

// ---------- 256^2 GEMM: 4-phase, fragment-pipelined ----------
// A: bf16 [E][T][K] row-major; B: bf16 [E][N][K]; bias fp32 [E][N].
template <bool RELU_BF16>
__global__ __launch_bounds__(512, 2) void gemm256_kernel(
    const ushort* __restrict__ A, const ushort* __restrict__ Bm,
    const float* __restrict__ bias, void* __restrict__ Cout,
    const int K, const int N) {
    // [buf p: A tile 32K | B tile 32K] x2 buffers = 128 KiB
    __shared__ __align__(16) char lds[131072];

    const int bid = blockIdx.x;
    const int e = bid & 7;             // expert == XCD
    const int s = bid >> 3;
    const int nb = N >> 8;             // n-blocks per expert (pow2)
    const int n0 = (s & (nb - 1)) * BN;
    const int m0 = (s >> __builtin_ctz(nb)) * BM;

    const ushort* Ae = A + (size_t)e * T * K + (size_t)m0 * K;
    const ushort* Be = Bm + (size_t)e * N * K + (size_t)n0 * K;

    const int tid = threadIdx.x;
    const int lane = tid & 63;
    const int wave = tid >> 6;
    const int wm = wave >> 2;          // 0..1
    const int wn = wave & 3;           // 0..3
    const int col = lane & 15;
    const int quad = lane >> 4;

    // staging: inverse-swizzled global source, linear LDS dest (rule #21)
    const int scc = (lane & 7) ^ (lane >> 3);
    const int srow = wave * 8 + (lane >> 3);
    const ushort* gA0 = Ae + (size_t)srow * K + scc * 8;
    const ushort* gB0 = Be + (size_t)srow * K + scc * 8;
    const int ldsA0 = wave * 1024;            // + p*65536 + h*16384 + i*8192
    const int ldsB0 = 32768 + wave * 1024;

    // frag-read swizzle: addr ^= ((row&7)<<4); row&7 == col&7 for every frag
    const int swz0 = ((quad ^ (col & 7)) << 4);
    const int swz1 = swz0 ^ 64;
    // interleaved ownership: rows wm*64+{0..63} and 128+wm*64+{0..63};
    //                        cols wn*32+{0..31} and 128+wn*32+{0..31}.
    const int aRow = (wm * 64 + col) * 128;   // byte base of A row-chunk0
    const int bRow = (wn * 32 + col) * 128;   // byte base of B col-chunk0

    const int NT = K / BK;

#define STAGE_A(p, h, kk) do {                                          \
        const ushort* g_ = gA0 + (size_t)(h) * 128 * K + (kk);          \
        char* l_ = lds + (p) * 65536 + ldsA0 + (h) * 16384;             \
        load16_to_lds(g_, l_);                                          \
        load16_to_lds(g_ + (size_t)64 * K, l_ + 8192);                  \
    } while (0)
#define STAGE_B(p, h, kk) do {                                          \
        const ushort* g_ = gB0 + (size_t)(h) * 128 * K + (kk);          \
        char* l_ = lds + (p) * 65536 + ldsB0 + (h) * 16384;             \
        load16_to_lds(g_, l_);                                          \
        load16_to_lds(g_ + (size_t)64 * K, l_ + 8192);                  \
    } while (0)
#define MFMA(a, b, c) __builtin_amdgcn_mfma_f32_16x16x32_bf16((a), (b), (c), 0, 0, 0)

    f32x4 acc[8][4] = {};
    frag8 A0f[8], A1f[8], Bf[4];

    // ---- prologue: tile0 full + A-h0/A-h1/B-h0 of tile1 (14 loads) ----
    STAGE_A(0, 0, 0); STAGE_A(0, 1, 0);
    STAGE_B(0, 0, 0); STAGE_B(0, 1, 0);
    STAGE_A(1, 0, BK); STAGE_A(1, 1, BK); STAGE_B(1, 0, BK);
    asm volatile("s_waitcnt vmcnt(6)" ::: "memory");   // tile0 (oldest 8) landed
    __builtin_amdgcn_s_barrier();
    __builtin_amdgcn_sched_barrier(0);

    // Quadrant order per tile: q00 (A0,B0) -> q10 (A1,B0) -> q11 (A1,B1) ->
    // q01 (A0,B1). Reads pipelined one phase ahead; only ph1 reads its own
    // operands (tile-boundary cost). Safety: A-h1(u)/B-h1(u) were drained by
    // tile u-1's end-vmcnt(6); stage slots identical to rounds 2-4.
#define TILE_ITER(u, p, pn) do {                                              \
        const int kB_ = ((u) + 1) * BK, kA_ = ((u) + 2) * BK;                 \
        const bool stB_ = (u) + 1 < NT, stA_ = (u) + 2 < NT;                  \
        const char* aT = lds + (p) * 65536 + aRow;                            \
        const char* bT = lds + (p) * 65536 + 32768 + bRow;                    \
        /* == ph1: read q00 operands, MFMA q00, read A1f for ph2 == */        \
        A0f[0] = *(const frag8*)(aT + swz0);                                  \
        A0f[1] = *(const frag8*)(aT + swz1);                                  \
        Bf[0] = *(const frag8*)(bT + swz0);                                   \
        Bf[1] = *(const frag8*)(bT + swz1);                                   \
        Bf[2] = *(const frag8*)(bT + 2048 + swz0);                            \
        Bf[3] = *(const frag8*)(bT + 2048 + swz1);                            \
        _Pragma("unroll")                                                     \
        for (int i = 1; i < 4; ++i) {                                         \
            A0f[i * 2 + 0] = *(const frag8*)(aT + i * 2048 + swz0);           \
            A0f[i * 2 + 1] = *(const frag8*)(aT + i * 2048 + swz1);           \
        }                                                                     \
        __builtin_amdgcn_s_setprio(1);                                        \
        _Pragma("unroll")                                                     \
        for (int i = 0; i < 4; ++i)                                           \
            _Pragma("unroll")                                                 \
            for (int j = 0; j < 2; ++j) {                                     \
                acc[i][j] = MFMA(A0f[i * 2 + 0], Bf[j * 2 + 0], acc[i][j]);   \
                acc[i][j] = MFMA(A0f[i * 2 + 1], Bf[j * 2 + 1], acc[i][j]);   \
            }                                                                 \
        __builtin_amdgcn_s_setprio(0);                                        \
        _Pragma("unroll")                                                     \
        for (int i = 0; i < 4; ++i) {                                         \
            A1f[i * 2 + 0] = *(const frag8*)(aT + 16384 + i * 2048 + swz0);   \
            A1f[i * 2 + 1] = *(const frag8*)(aT + 16384 + i * 2048 + swz1);   \
        }                                                                     \
        if (stB_) STAGE_B(pn, 1, kB_);                                        \
        __builtin_amdgcn_s_barrier();                                         \
        __builtin_amdgcn_sched_barrier(0);                                    \
        /* == ph2: MFMA q10 (A1f in flight 1 phase); refill Bf<-B-h1 == */    \
        __builtin_amdgcn_s_setprio(1);                                        \
        _Pragma("unroll")                                                     \
        for (int i = 0; i < 4; ++i)                                           \
            _Pragma("unroll")                                                 \
            for (int j = 0; j < 2; ++j) {                                     \
                acc[4 + i][j] = MFMA(A1f[i * 2 + 0], Bf[j * 2 + 0], acc[4 + i][j]); \
                acc[4 + i][j] = MFMA(A1f[i * 2 + 1], Bf[j * 2 + 1], acc[4 + i][j]); \
            }                                                                 \
        __builtin_amdgcn_s_setprio(0);                                        \
        _Pragma("unroll")                                                     \
        for (int j = 0; j < 2; ++j) {                                         \
            Bf[j * 2 + 0] = *(const frag8*)(bT + 16384 + j * 2048 + swz0);    \
            Bf[j * 2 + 1] = *(const frag8*)(bT + 16384 + j * 2048 + swz1);    \
        }                                                                     \
        if (stA_) STAGE_A(p, 0, kA_);                                         \
        __builtin_amdgcn_s_barrier();                                         \
        __builtin_amdgcn_sched_barrier(0);                                    \
        /* == ph3: MFMA q11 (Bf=B1 in flight 1 phase); 0 reads == */          \
        __builtin_amdgcn_s_setprio(1);                                        \
        _Pragma("unroll")                                                     \
        for (int i = 0; i < 4; ++i)                                           \
            _Pragma("unroll")                                                 \
            for (int j = 0; j < 2; ++j) {                                     \
                acc[4 + i][2 + j] = MFMA(A1f[i * 2 + 0], Bf[j * 2 + 0], acc[4 + i][2 + j]); \
                acc[4 + i][2 + j] = MFMA(A1f[i * 2 + 1], Bf[j * 2 + 1], acc[4 + i][2 + j]); \
            }                                                                 \
        __builtin_amdgcn_s_setprio(0);                                        \
        if (stA_) STAGE_A(p, 1, kA_);                                         \
        __builtin_amdgcn_s_barrier();                                         \
        __builtin_amdgcn_sched_barrier(0);                                    \
        /* == ph4: MFMA q01 (all operands in regs); 0 reads == */             \
        __builtin_amdgcn_s_setprio(1);                                        \
        _Pragma("unroll")                                                     \
        for (int i = 0; i < 4; ++i)                                           \
            _Pragma("unroll")                                                 \
            for (int j = 0; j < 2; ++j) {                                     \
                acc[i][2 + j] = MFMA(A0f[i * 2 + 0], Bf[j * 2 + 0], acc[i][2 + j]); \
                acc[i][2 + j] = MFMA(A0f[i * 2 + 1], Bf[j * 2 + 1], acc[i][2 + j]); \
            }                                                                 \
        __builtin_amdgcn_s_setprio(0);                                        \
        if (stA_) STAGE_B(p, 0, kA_);                                         \
        /* in flight after wait: A-h0/A-h1/B-h0 of tile u+2 = 3 halves */     \
        if (stA_) {                                                           \
            asm volatile("s_waitcnt vmcnt(6)" ::: "memory");                  \
        } else if (stB_) {                                                    \
            asm volatile("s_waitcnt vmcnt(0)" ::: "memory");                  \
        }                                                                     \
        __builtin_amdgcn_s_barrier();                                         \
        __builtin_amdgcn_sched_barrier(0);                                    \
    } while (0)

    for (int v = 0; v < NT / 2; ++v) {
        TILE_ITER(2 * v, 0, 1);
        TILE_ITER(2 * v + 1, 1, 0);
    }
#undef TILE_ITER

    // ---- epilogue: interleaved ownership mapping ----
    const float* be = bias + (size_t)e * N;
#pragma unroll
    for (int j = 0; j < 4; ++j) {
        const int nn = n0 + wn * 32 + (j & 1) * 16 + (j >> 1) * 128 + col;
        const float bv = be[nn];
#pragma unroll
        for (int i = 0; i < 8; ++i) {
            const int mb = m0 + wm * 64 + (i & 3) * 16 + (i >> 2) * 128 + quad * 4;
#pragma unroll
            for (int r = 0; r < 4; ++r) {
                float v = acc[i][j][r] + bv;
                if (RELU_BF16) {
                    v = v > 0.f ? v : 0.f;
                    ((ushort*)Cout)[(size_t)e * T * N + (size_t)(mb + r) * N + nn] = f2bf(v);
                } else {
                    ((float*)Cout)[(size_t)e * T * N + (size_t)(mb + r) * N + nn] = v;
                }
            }
        }
    }
#undef STAGE_A
#undef STAGE_B
#undef MFMA
}

// ---------- round-1 fallback (ws too small for prep regions) ----------

constexpr int FBM = 128, FBN = 128, FBK = 32;
constexpr int FLDK = FBK + 16;

__global__ __launch_bounds__(256) void fb_gemm1_kernel(
    const float* __restrict__ x, const float* __restrict__ w1,
    const float* __restrict__ b1, ushort* __restrict__ y1) {
    __shared__ __align__(16) ushort As[FBM * FLDK];
    __shared__ __align__(16) ushort Bs[FBN * FLDK];
    const int e = blockIdx.z, m0 = blockIdx.y * FBM, n0 = blockIdx.x * FBN;
    const float* xa = x + (size_t)e * T * D + (size_t)m0 * D;
    const float* wb = w1 + (size_t)e * D * H;
    const int tid = threadIdx.x, lane = tid & 63, wave = tid >> 6;
    const int waveM = (wave >> 1) * 64, waveN = (wave & 1) * 64;
    const int col = lane & 15, quad = lane >> 4;
    const int ar = tid >> 3, ak = (tid & 7) * 4;
    const int bn = tid & 127, bk = (tid >> 7) * 16;
    f32x4 acc[4][4] = {};
    for (int k0 = 0; k0 < D; k0 += FBK) {
#pragma unroll
        for (int p = 0; p < 4; ++p) {
            const float4 v = *(const float4*)(xa + (size_t)(ar + 32 * p) * D + k0 + ak);
            ushort* dst = &As[(ar + 32 * p) * FLDK + ak];
            dst[0] = f2bf(v.x); dst[1] = f2bf(v.y); dst[2] = f2bf(v.z); dst[3] = f2bf(v.w);
        }
        {
            ushort tmp[16];
#pragma unroll
            for (int j = 0; j < 16; ++j)
                tmp[j] = f2bf(wb[(size_t)(k0 + bk + j) * H + n0 + bn]);
            ushort* dst = &Bs[bn * FLDK + bk];
#pragma unroll
            for (int j = 0; j < 16; ++j) dst[j] = tmp[j];
        }
        __syncthreads();
        frag8 af[4], bf[4];
#pragma unroll
        for (int i = 0; i < 4; ++i) {
            af[i] = *(const frag8*)&As[(waveM + i * 16 + col) * FLDK + quad * 8];
            bf[i] = *(const frag8*)&Bs[(waveN + i * 16 + col) * FLDK + quad * 8];
        }
#pragma unroll
        for (int i = 0; i < 4; ++i)
#pragma unroll
            for (int j = 0; j < 4; ++j)
                acc[i][j] = __builtin_amdgcn_mfma_f32_16x16x32_bf16(af[i], bf[j], acc[i][j], 0, 0, 0);
        __syncthreads();
    }
    const float* be = b1 + (size_t)e * H;
    ushort* ye = y1 + (size_t)e * T * H;
#pragma unroll
    for (int j = 0; j < 4; ++j) {
        const int n = n0 + waveN + j * 16 + col;
        const float bias = be[n];
#pragma unroll
        for (int i = 0; i < 4; ++i) {
            const int mb = m0 + waveM + i * 16 + quad * 4;
#pragma unroll
            for (int r = 0; r < 4; ++r) {
                float v = acc[i][j][r] + bias;
                v = v > 0.f ? v : 0.f;
                ye[(size_t)(mb + r) * H + n] = f2bf(v);
            }
        }
    }
}

__global__ __launch_bounds__(256) void fb_gemm2_kernel(
    const ushort* __restrict__ y1, const float* __restrict__ w2,
    const float* __restrict__ b2, float* __restrict__ out) {
    __shared__ __align__(16) ushort As[FBM * FLDK];
    __shared__ __align__(16) ushort Bs[FBN * FLDK];
    const int e = blockIdx.z, m0 = blockIdx.y * FBM, n0 = blockIdx.x * FBN;
    const ushort* ya = y1 + (size_t)e * T * H + (size_t)m0 * H;
    const float* wb = w2 + (size_t)e * H * D;
    const int tid = threadIdx.x, lane = tid & 63, wave = tid >> 6;
    const int waveM = (wave >> 1) * 64, waveN = (wave & 1) * 64;
    const int col = lane & 15, quad = lane >> 4;
    const int ar = tid >> 2, ak = (tid & 3) * 8;
    const int bn = tid & 127, bk = (tid >> 7) * 16;
    f32x4 acc[4][4] = {};
    for (int k0 = 0; k0 < H; k0 += FBK) {
#pragma unroll
        for (int p = 0; p < 2; ++p)
            *(frag8*)&As[(ar + 64 * p) * FLDK + ak] =
                *(const frag8*)(ya + (size_t)(ar + 64 * p) * H + k0 + ak);
        {
            ushort tmp[16];
#pragma unroll
            for (int j = 0; j < 16; ++j)
                tmp[j] = f2bf(wb[(size_t)(k0 + bk + j) * D + n0 + bn]);
            ushort* dst = &Bs[bn * FLDK + bk];
#pragma unroll
            for (int j = 0; j < 16; ++j) dst[j] = tmp[j];
        }
        __syncthreads();
        frag8 af[4], bf[4];
#pragma unroll
        for (int i = 0; i < 4; ++i) {
            af[i] = *(const frag8*)&As[(waveM + i * 16 + col) * FLDK + quad * 8];
            bf[i] = *(const frag8*)&Bs[(waveN + i * 16 + col) * FLDK + quad * 8];
        }
#pragma unroll
        for (int i = 0; i < 4; ++i)
#pragma unroll
            for (int j = 0; j < 4; ++j)
                acc[i][j] = __builtin_amdgcn_mfma_f32_16x16x32_bf16(af[i], bf[j], acc[i][j], 0, 0, 0);
        __syncthreads();
    }
    const float* be = b2 + (size_t)e * D;
    float* oe = out + (size_t)e * T * D;
#pragma unroll
    for (int j = 0; j < 4; ++j) {
        const int n = n0 + waveN + j * 16 + col;
        const float bias = be[n];
#pragma unroll
        for (int i = 0; i < 4; ++i) {
            const int mb = m0 + waveM + i * 16 + quad * 4;
#pragma unroll
            for (int r = 0; r < 4; ++r)
                oe[(size_t)(mb + r) * D + n] = acc[i][j][r] + bias;
        }
    }
}

extern "C" void kernel_launch(void* const* d_in, const int* in_sizes, int n_in,
                              void* d_out, int out_size, void* d_ws, size_t ws_size,
                              hipStream_t stream) {
    const float* x  = (const float*)d_in[0];   // [E,T,D]
    const float* w1 = (const float*)d_in[1];   // [E,D,H]
    const float* b1 = (const float*)d_in[2];   // [E,1,H]
    const float* w2 = (const float*)d_in[3];   // [E,H,D]
    const float* b2 = (const float*)d_in[4];   // [E,1,D]
    float* out = (float*)d_out;                // [E,T,D]

    const size_t y1_bytes = (size_t)E * T * H * 2;  // 128 MB
    const size_t wt_bytes = (size_t)E * D * H * 2;  //  64 MB (shared w1t/w2t)
    const size_t xb_bytes = (size_t)E * T * D * 2;  //  32 MB
    const size_t need = y1_bytes + wt_bytes + xb_bytes;  // 224 MB

    if (ws_size >= need) {
        ushort* y1 = (ushort*)d_ws;
        ushort* wt = (ushort*)((char*)d_ws + y1_bytes);
        ushort* xb = (ushort*)((char*)d_ws + y1_bytes + wt_bytes);

        // 1. x -> bf16
        cvt_bf16_kernel<<<(E * T * D) / (256 * 4), 256, 0, stream>>>(x, xb);
        // 2. w1 [E][D][H] -> wt [E][H][D] bf16
        transpose_cvt_kernel<<<dim3(H / 64, D / 64, E), 256, 0, stream>>>(w1, wt, D, H);
        // 3. gemm1: y1 = relu(xb @ w1 + b1), bf16   (8x8x16 = 1024 blocks)
        gemm256_kernel<true><<<E * (T / BM) * (H / BN), 512, 0, stream>>>(xb, wt, b1, y1, D, H);
        // 4. w2 [E][H][D] -> wt [E][D][H] bf16 (region reuse)
        transpose_cvt_kernel<<<dim3(D / 64, H / 64, E), 256, 0, stream>>>(w2, wt, H, D);
        // 5. gemm2: out = y1 @ w2 + b2, fp32        (8x8x4 = 256 blocks)
        gemm256_kernel<false><<<E * (T / BM) * (D / BN), 512, 0, stream>>>(y1, wt, b2, out, H, D);
    } else {
        ushort* y1 = (ushort*)d_ws;
        fb_gemm1_kernel<<<dim3(H / FBN, T / FBM, E), 256, 0, stream>>>(x, w1, b1, y1);
        fb_gemm2_kernel<<<dim3(D / FBN, T / FBM, E), 256, 0, stream>>>(y1, w2, b2, out);
    }
}